// Round 1
// baseline (1961.652 us; speedup 1.0000x reference)
//
#include <hip/hip_runtime.h>
#include <math.h>

#define EPSV 1e-5f
#define GF_RELU 1
#define GF_ACCUM 2

typedef unsigned long long u64;
typedef unsigned int u32;

static const int Bn = 8;
static const int Nmax = 2048;
static const int KNN_K = 8;

// ---------------- precompute: fold BN into scale/bias, zero picks ----------------
__global__ void precompute_kernel(const float* __restrict__ bn_g, const float* __restrict__ bn_b,
                                  const float* __restrict__ bp1,
                                  float* __restrict__ sc, float* __restrict__ bb,
                                  float* __restrict__ picks) {
  int t = threadIdx.x;
  if (t < 128) {
    float s = bn_g[t] / sqrtf(1.0f + EPSV);
    sc[t] = s;
    bb[t] = bp1[t] * s + bn_b[t];
  }
  for (int i = t; i < Bn * 256; i += blockDim.x) picks[i] = 0.0f;
}

// ---------------- KNN: one wave per node, exact (d2,idx) lexicographic top-8 ----
__global__ void knn_kernel(const float* __restrict__ cent, int Ni, int* __restrict__ knn_idx) {
  int i = blockIdx.x, b = blockIdx.y, lane = threadIdx.x;
  const float* cb = cent + (size_t)b * Ni * 2;
  float xi = cb[2 * i], yi = cb[2 * i + 1];
  u64 best[8];
#pragma unroll
  for (int t = 0; t < 8; ++t) best[t] = ~0ULL;
  for (int j = lane; j < Ni; j += 64) {
    float dx = __fsub_rn(xi, cb[2 * j]);
    float dy = __fsub_rn(yi, cb[2 * j + 1]);
    float d2 = __fadd_rn(__fmul_rn(dx, dx), __fmul_rn(dy, dy));
    u64 key = ((u64)__float_as_uint(d2) << 32) | (u32)j;
    if (key < best[7]) {
      best[7] = key;
      for (int t = 7; t > 0; --t) {
        if (best[t] < best[t - 1]) { u64 tmp = best[t - 1]; best[t - 1] = best[t]; best[t] = tmp; }
        else break;
      }
    }
  }
  int ptr = 0;
  for (int r = 0; r < KNN_K; ++r) {
    u64 mine = (ptr < 8) ? best[ptr] : ~0ULL;
    u64 mn = mine;
    for (int off = 32; off >= 1; off >>= 1) {
      u64 o = __shfl_xor(mn, off, 64);
      if (o < mn) mn = o;
    }
    if (mine == mn) ptr++;
    if (lane == 0) knn_idx[((size_t)(b * Ni + i)) * KNN_K + r] = (int)(mn & 0xffffffffULL);
  }
}

// ---------------- adjacency bitmask: A = mask | mask^T -------------------------
__global__ void build_adj_kernel(const int* __restrict__ knn_idx, u32* __restrict__ adj, int Ni) {
  int e = blockIdx.x * blockDim.x + threadIdx.x;
  int total = Bn * Ni * KNN_K;
  if (e >= total) return;
  int b = e / (Ni * KNN_K);
  int rem = e % (Ni * KNN_K);
  int r = rem / KNN_K;
  int j = knn_idx[e];
  atomicOr(&adj[((size_t)(b * Nmax + r)) * 64 + (j >> 5)], 1u << (j & 31));
  atomicOr(&adj[((size_t)(b * Nmax + j)) * 64 + (r >> 5)], 1u << (r & 31));
}

// ---------------- layernorm over H=128, one block per node ---------------------
__global__ void layernorm_kernel(const float* __restrict__ x, const float* __restrict__ g,
                                 const float* __restrict__ be, float* __restrict__ xn) {
  int node = blockIdx.x;
  int t = threadIdx.x;
  __shared__ float red[128];
  float v = x[(size_t)node * 128 + t];
  red[t] = v;
  __syncthreads();
  for (int s = 64; s > 0; s >>= 1) { if (t < s) red[t] += red[t + s]; __syncthreads(); }
  float mean = red[0] / 128.0f;
  __syncthreads();
  float d = v - mean;
  red[t] = d * d;
  __syncthreads();
  for (int s = 64; s > 0; s >>= 1) { if (t < s) red[t] += red[t + s]; __syncthreads(); }
  float var = red[0] / 128.0f;
  xn[(size_t)node * 128 + t] = d * rsqrtf(var + EPSV) * g[t] + be[t];
}

// ---------------- neighbor-mean aggregation + degree ---------------------------
__global__ void aggregate_kernel(const u32* __restrict__ adj, const float* __restrict__ xn,
                                 float* __restrict__ m, float* __restrict__ dinv, int Ni) {
  int i = blockIdx.x, b = blockIdx.y, t = threadIdx.x;
  __shared__ int cnt;
  extern __shared__ int list[];
  if (t == 0) cnt = 0;
  __syncthreads();
  int wpr = Ni >> 5;
  for (int w = t; w < wpr; w += blockDim.x) {
    u32 bits = adj[((size_t)(b * Nmax + i)) * 64 + w];
    while (bits) {
      int bit = __ffs(bits) - 1;
      bits &= bits - 1;
      int pos = atomicAdd(&cnt, 1);
      list[pos] = (w << 5) + bit;
    }
  }
  __syncthreads();
  int d = cnt;
  float acc = 0.0f;
  for (int k = 0; k < d; ++k) acc += xn[((size_t)b * Ni + list[k]) * 128 + t];
  m[((size_t)b * Ni + i) * 128 + t] = acc / (float)d;
  if (t == 0) dinv[b * Nmax + i] = 1.0f / sqrtf((float)d);
}

// ---------------- generic fp32 GEMM: C = f((A@W [+ A2@W2]) * scale + bias) -----
__global__ __launch_bounds__(256) void gemm_kernel(
    const float* __restrict__ A, const float* __restrict__ W,
    const float* __restrict__ A2, const float* __restrict__ W2,
    const float* __restrict__ scale, const float* __restrict__ bias,
    float* __restrict__ C, int M, int N, int K, int flags) {
  __shared__ float As[16][65];
  __shared__ float Bs[16][65];
  int tx = threadIdx.x & 15, ty = threadIdx.x >> 4;
  int colBase = blockIdx.x * 64, rowBase = blockIdx.y * 64;
  float acc[4][4] = {};
  int npass = A2 ? 2 : 1;
  for (int pass = 0; pass < npass; ++pass) {
    const float* Ap = pass ? A2 : A;
    const float* Wp = pass ? W2 : W;
    for (int k0 = 0; k0 < K; k0 += 16) {
      for (int tdx = threadIdx.x; tdx < 64 * 16; tdx += 256) {
        int r = tdx >> 4, kk = tdx & 15;
        As[kk][r] = Ap[(size_t)(rowBase + r) * K + k0 + kk];
      }
      for (int tdx = threadIdx.x; tdx < 16 * 64; tdx += 256) {
        int kk = tdx >> 6, cc = tdx & 63;
        Bs[kk][cc] = Wp[(size_t)(k0 + kk) * N + colBase + cc];
      }
      __syncthreads();
#pragma unroll
      for (int kk = 0; kk < 16; ++kk) {
        float a[4], bv[4];
#pragma unroll
        for (int r = 0; r < 4; ++r) a[r] = As[kk][ty * 4 + r];
#pragma unroll
        for (int c = 0; c < 4; ++c) bv[c] = Bs[kk][tx * 4 + c];
#pragma unroll
        for (int r = 0; r < 4; ++r)
#pragma unroll
          for (int c = 0; c < 4; ++c) acc[r][c] += a[r] * bv[c];
      }
      __syncthreads();
    }
  }
#pragma unroll
  for (int r = 0; r < 4; ++r) {
    int row = rowBase + ty * 4 + r;
#pragma unroll
    for (int c = 0; c < 4; ++c) {
      int col = colBase + tx * 4 + c;
      float v = acc[r][c];
      if (scale) v *= scale[col];
      if (bias) v += bias[col];
      if (flags & GF_RELU) v = fmaxf(v, 0.0f);
      size_t o = (size_t)row * N + col;
      if (flags & GF_ACCUM) C[o] += v;
      else C[o] = v;
    }
  }
}

// ---------------- q = x@Wq ; p = dinv*q ---------------------------------------
__global__ void qp_kernel(const float* __restrict__ x, const float* __restrict__ Wq,
                          const float* __restrict__ dinv, float* __restrict__ p, int Ni) {
  int node = blockIdx.x;
  int lane = threadIdx.x;
  int b = node / Ni, i = node % Ni;
  float v = x[(size_t)node * 128 + lane] * Wq[lane] +
            x[(size_t)node * 128 + 64 + lane] * Wq[64 + lane];
  for (int off = 32; off >= 1; off >>= 1) v += __shfl_xor(v, off, 64);
  if (lane == 0) p[b * Nmax + i] = dinv[b * Nmax + i] * v;
}

// ---------------- s = dinv * (A @ p) + bq -------------------------------------
__global__ void score_kernel(const u32* __restrict__ adj, const float* __restrict__ p,
                             const float* __restrict__ dinv, const float* __restrict__ bq,
                             float* __restrict__ s, int Ni) {
  int i = blockIdx.x, b = blockIdx.y, lane = threadIdx.x;
  int wpr = Ni >> 5;
  float acc = 0.0f;
  if (lane < wpr) {
    u32 bits = adj[((size_t)(b * Nmax + i)) * 64 + lane];
    while (bits) {
      int bit = __ffs(bits) - 1;
      bits &= bits - 1;
      acc += p[b * Nmax + (lane << 5) + bit];
    }
  }
  for (int off = 32; off >= 1; off >>= 1) acc += __shfl_xor(acc, off, 64);
  if (lane == 0) s[b * Nmax + i] = dinv[b * Nmax + i] * acc + bq[0];
}

// ---------------- top-k via bitonic sort (desc value, asc index) ---------------
__global__ void topk_kernel(const float* __restrict__ s, int Ni, int* __restrict__ topi) {
  int b = blockIdx.x;
  int t = threadIdx.x;
  int T = blockDim.x;
  extern __shared__ u64 keys[];
  for (int e = t; e < Ni; e += T) {
    u32 u = __float_as_uint(s[b * Nmax + e]);
    u32 mono = (u & 0x80000000u) ? ~u : (u | 0x80000000u);
    keys[e] = ((u64)(~mono) << 32) | (u32)e;
  }
  __syncthreads();
  for (int kk = 2; kk <= Ni; kk <<= 1) {
    for (int j = kk >> 1; j > 0; j >>= 1) {
      for (int e = t; e < Ni; e += T) {
        int ixj = e ^ j;
        if (ixj > e) {
          u64 a = keys[e], b2 = keys[ixj];
          bool up = ((e & kk) == 0);
          if (up ? (a > b2) : (a < b2)) { keys[e] = b2; keys[ixj] = a; }
        }
      }
      __syncthreads();
    }
  }
  int kkeep = Ni >> 1;
  for (int e = t; e < kkeep; e += T) topi[b * 1024 + e] = (int)(keys[e] & 0xffffffffULL);
}

// ---------------- gather + tanh gate ------------------------------------------
__global__ void gather_kernel(const float* __restrict__ x, const float* __restrict__ c,
                              const float* __restrict__ s, const int* __restrict__ topi,
                              float* __restrict__ xo, float* __restrict__ co, int Ni) {
  int inew = blockIdx.x, b = blockIdx.y, t = threadIdx.x;
  int kkeep = Ni >> 1;
  int old = topi[b * 1024 + inew];
  float gate = tanhf(s[b * Nmax + old]);
  xo[((size_t)b * kkeep + inew) * 128 + t] = x[((size_t)b * Ni + old) * 128 + t] * gate;
  if (t < 2) co[((size_t)b * kkeep + inew) * 2 + t] = c[((size_t)b * Ni + old) * 2 + t];
}

// ---------------- picks += [max ; mean] ---------------------------------------
__global__ void picks_kernel(const float* __restrict__ x, float* __restrict__ picks, int kkeep) {
  int b = blockIdx.x, t = threadIdx.x;
  float mx = -INFINITY, sm = 0.0f;
  for (int i = 0; i < kkeep; ++i) {
    float v = x[((size_t)b * kkeep + i) * 128 + t];
    mx = fmaxf(mx, v);
    sm += v;
  }
  picks[b * 256 + t] += mx;
  picks[b * 256 + 128 + t] += sm / (float)kkeep;
}

// ---------------- final 2-layer MLP -------------------------------------------
__global__ void final_kernel(const float* __restrict__ picks, const float* __restrict__ Wf1,
                             const float* __restrict__ bf1, const float* __restrict__ Wf2,
                             const float* __restrict__ bf2, float* __restrict__ out) {
  int b = blockIdx.x, t = threadIdx.x;
  __shared__ float pk[256];
  __shared__ float fm[128];
  pk[t] = picks[b * 256 + t];
  pk[t + 128] = picks[b * 256 + 128 + t];
  __syncthreads();
  float acc = bf1[t];
  for (int k = 0; k < 256; ++k) acc += pk[k] * Wf1[k * 128 + t];
  fm[t] = fmaxf(acc, 0.0f);
  __syncthreads();
  if (t < 32) {
    float a2 = bf2[t];
    for (int k = 0; k < 128; ++k) a2 += fm[k] * Wf2[k * 32 + t];
    out[b * 32 + t] = fmaxf(a2, 0.0f);
  }
}

extern "C" void kernel_launch(void* const* d_in, const int* in_sizes, int n_in,
                              void* d_out, int out_size, void* d_ws, size_t ws_size,
                              hipStream_t stream) {
  const float* feats = (const float*)d_in[0];
  const float* cent  = (const float*)d_in[1];
  const float* Wp1 = (const float*)d_in[2];
  const float* bp1 = (const float*)d_in[3];
  const float* bn_g = (const float*)d_in[4];
  const float* bn_b = (const float*)d_in[5];
  const float* Wp2 = (const float*)d_in[6];
  const float* bp2 = (const float*)d_in[7];
  const float* g1  = (const float*)d_in[8];
  const float* be1 = (const float*)d_in[9];
  const float* g2  = (const float*)d_in[10];
  const float* be2 = (const float*)d_in[11];
  const float* Ws  = (const float*)d_in[12];
  const float* Wn  = (const float*)d_in[13];
  const float* bs  = (const float*)d_in[14];
  const float* Wg  = (const float*)d_in[15];
  const float* bg  = (const float*)d_in[16];
  const float* W1  = (const float*)d_in[17];
  const float* b1  = (const float*)d_in[18];
  const float* W2  = (const float*)d_in[19];
  const float* b2  = (const float*)d_in[20];
  const float* Wq  = (const float*)d_in[21];
  const float* bq  = (const float*)d_in[22];
  const float* Wf1 = (const float*)d_in[23];
  const float* bf1 = (const float*)d_in[24];
  const float* Wf2 = (const float*)d_in[25];
  const float* bf2 = (const float*)d_in[26];
  float* out = (float*)d_out;

  float* ws = (float*)d_ws;
  const size_t SZX = (size_t)Bn * Nmax * 128;
  float* X0 = ws;    ws += SZX;
  float* X1 = ws;    ws += SZX;
  float* BA = ws;    ws += SZX;   // xn / xn2
  float* BB = ws;    ws += SZX;   // m / ffn tmp
  float* HB = ws;    ws += SZX;   // per-head h
  float* C0 = ws;    ws += (size_t)Bn * Nmax * 2;
  float* C1 = ws;    ws += (size_t)Bn * Nmax * 2;
  float* SC = ws;    ws += 128;
  float* BBv = ws;   ws += 128;
  float* DINV = ws;  ws += Bn * Nmax;
  float* PV = ws;    ws += Bn * Nmax;
  float* SS = ws;    ws += Bn * Nmax;
  float* PICKS = ws; ws += Bn * 256;
  int* KNN = (int*)ws;  ws += (size_t)Bn * Nmax * KNN_K;
  int* TOPI = (int*)ws; ws += Bn * 1024;
  u32* ADJ = (u32*)ws;  // Bn * Nmax * 64 u32

  hipLaunchKernelGGL(precompute_kernel, dim3(1), dim3(256), 0, stream,
                     bn_g, bn_b, bp1, SC, BBv, PICKS);

  // ---- preconv ----
  const int M0 = Bn * Nmax;
  hipLaunchKernelGGL(gemm_kernel, dim3(2, M0 / 64), dim3(256), 0, stream,
                     feats, Wp1, (const float*)nullptr, (const float*)nullptr,
                     SC, BBv, BA, M0, 128, 512, GF_RELU);
  hipLaunchKernelGGL(gemm_kernel, dim3(2, M0 / 64), dim3(256), 0, stream,
                     BA, Wp2, (const float*)nullptr, (const float*)nullptr,
                     (const float*)nullptr, bp2, X0, M0, 128, 128, 0);

  float* xc = X0;
  float* xo = X1;
  const float* cc = cent;
  float* co = C0;
  int Ni = Nmax;
  for (int L = 0; L < 3; ++L) {
    int M = Bn * Ni;
    hipLaunchKernelGGL(knn_kernel, dim3(Ni, Bn), dim3(64), 0, stream, cc, Ni, KNN);
    hipMemsetAsync(ADJ, 0, (size_t)Bn * Nmax * 64 * sizeof(u32), stream);
    int tot = Bn * Ni * KNN_K;
    hipLaunchKernelGGL(build_adj_kernel, dim3((tot + 255) / 256), dim3(256), 0, stream,
                       KNN, ADJ, Ni);
    hipLaunchKernelGGL(layernorm_kernel, dim3(M), dim3(128), 0, stream,
                       xc, g1 + L * 128, be1 + L * 128, BA);
    hipLaunchKernelGGL(aggregate_kernel, dim3(Ni, Bn), dim3(128), Ni * sizeof(int), stream,
                       ADJ, BA, BB, DINV, Ni);
    for (int hh = 0; hh < 4; ++hh) {
      hipLaunchKernelGGL(gemm_kernel, dim3(2, M / 64), dim3(256), 0, stream,
                         BA, Ws + ((size_t)(L * 4 + hh)) * 128 * 128,
                         BB, Wn + ((size_t)(L * 4 + hh)) * 128 * 128,
                         (const float*)nullptr, bs + (L * 4 + hh) * 128,
                         HB, M, 128, 128, GF_RELU);
      hipLaunchKernelGGL(gemm_kernel, dim3(2, M / 64), dim3(256), 0, stream,
                         HB, Wg + ((size_t)L * 512 + hh * 128) * 128,
                         (const float*)nullptr, (const float*)nullptr,
                         (const float*)nullptr, (hh == 0) ? (bg + L * 128) : (const float*)nullptr,
                         xc, M, 128, 128, GF_ACCUM);
    }
    hipLaunchKernelGGL(layernorm_kernel, dim3(M), dim3(128), 0, stream,
                       xc, g2 + L * 128, be2 + L * 128, BA);
    hipLaunchKernelGGL(gemm_kernel, dim3(2, M / 64), dim3(256), 0, stream,
                       BA, W1 + (size_t)L * 128 * 128, (const float*)nullptr, (const float*)nullptr,
                       (const float*)nullptr, b1 + L * 128, BB, M, 128, 128, GF_RELU);
    hipLaunchKernelGGL(gemm_kernel, dim3(2, M / 64), dim3(256), 0, stream,
                       BB, W2 + (size_t)L * 128 * 128, (const float*)nullptr, (const float*)nullptr,
                       (const float*)nullptr, b2 + L * 128, xc, M, 128, 128, GF_ACCUM);
    hipLaunchKernelGGL(qp_kernel, dim3(M), dim3(64), 0, stream, xc, Wq + L * 128, DINV, PV, Ni);
    hipLaunchKernelGGL(score_kernel, dim3(Ni, Bn), dim3(64), 0, stream, ADJ, PV, DINV, bq + L, SS, Ni);
    hipLaunchKernelGGL(topk_kernel, dim3(Bn), dim3(1024), Ni * sizeof(u64), stream, SS, Ni, TOPI);
    int kkeep = Ni >> 1;
    hipLaunchKernelGGL(gather_kernel, dim3(kkeep, Bn), dim3(128), 0, stream,
                       xc, cc, SS, TOPI, xo, co, Ni);
    hipLaunchKernelGGL(picks_kernel, dim3(Bn), dim3(128), 0, stream, xo, PICKS, kkeep);
    float* tmp = xc; xc = xo; xo = tmp;
    cc = co;
    co = (co == C0) ? C1 : C0;
    Ni = kkeep;
  }
  hipLaunchKernelGGL(final_kernel, dim3(Bn), dim3(128), 0, stream,
                     PICKS, Wf1, bf1, Wf2, bf2, out);
}

// Round 2
// 1558.511 us; speedup vs baseline: 1.2587x; 1.2587x over previous
//
#include <hip/hip_runtime.h>
#include <math.h>

#define EPSV 1e-5f
#define GF_RELU 1
#define GF_ACCUM 2

typedef unsigned long long u64;
typedef unsigned int u32;

static const int Bn = 8;
static const int Nmax = 2048;
static const int KNN_K = 8;

// ---------------- precompute: fold BN into scale/bias, zero picks ----------------
__global__ void precompute_kernel(const float* __restrict__ bn_g, const float* __restrict__ bn_b,
                                  const float* __restrict__ bp1,
                                  float* __restrict__ sc, float* __restrict__ bb,
                                  float* __restrict__ picks) {
  int t = threadIdx.x;
  if (t < 128) {
    float s = bn_g[t] / sqrtf(1.0f + EPSV);
    sc[t] = s;
    bb[t] = bp1[t] * s + bn_b[t];
  }
  for (int i = t; i < Bn * 256; i += blockDim.x) picks[i] = 0.0f;
}

// ---------------- KNN: one wave per node, exact (d2,idx) lexicographic top-8 ----
__global__ void knn_kernel(const float* __restrict__ cent, int Ni, int* __restrict__ knn_idx) {
  int i = blockIdx.x, b = blockIdx.y, lane = threadIdx.x;
  const float* cb = cent + (size_t)b * Ni * 2;
  float xi = cb[2 * i], yi = cb[2 * i + 1];
  u64 best[8];
#pragma unroll
  for (int t = 0; t < 8; ++t) best[t] = ~0ULL;
  for (int j = lane; j < Ni; j += 64) {
    float dx = __fsub_rn(xi, cb[2 * j]);
    float dy = __fsub_rn(yi, cb[2 * j + 1]);
    float d2 = __fadd_rn(__fmul_rn(dx, dx), __fmul_rn(dy, dy));
    u64 key = ((u64)__float_as_uint(d2) << 32) | (u32)j;
    if (key < best[7]) {
      best[7] = key;
      for (int t = 7; t > 0; --t) {
        if (best[t] < best[t - 1]) { u64 tmp = best[t - 1]; best[t - 1] = best[t]; best[t] = tmp; }
        else break;
      }
    }
  }
  int ptr = 0;
  for (int r = 0; r < KNN_K; ++r) {
    u64 mine = (ptr < 8) ? best[ptr] : ~0ULL;
    u64 mn = mine;
    for (int off = 32; off >= 1; off >>= 1) {
      u64 o = __shfl_xor(mn, off, 64);
      if (o < mn) mn = o;
    }
    if (mine == mn) ptr++;
    if (lane == 0) knn_idx[((size_t)(b * Ni + i)) * KNN_K + r] = (int)(mn & 0xffffffffULL);
  }
}

// ---------------- adjacency bitmask: A = mask | mask^T -------------------------
__global__ void build_adj_kernel(const int* __restrict__ knn_idx, u32* __restrict__ adj, int Ni) {
  int e = blockIdx.x * blockDim.x + threadIdx.x;
  int total = Bn * Ni * KNN_K;
  if (e >= total) return;
  int b = e / (Ni * KNN_K);
  int rem = e % (Ni * KNN_K);
  int r = rem / KNN_K;
  int j = knn_idx[e];
  atomicOr(&adj[((size_t)(b * Nmax + r)) * 64 + (j >> 5)], 1u << (j & 31));
  atomicOr(&adj[((size_t)(b * Nmax + j)) * 64 + (r >> 5)], 1u << (r & 31));
}

// ---------------- layernorm over H=128, one block per node ---------------------
__global__ void layernorm_kernel(const float* __restrict__ x, const float* __restrict__ g,
                                 const float* __restrict__ be, float* __restrict__ xn) {
  int node = blockIdx.x;
  int t = threadIdx.x;
  __shared__ float red[128];
  float v = x[(size_t)node * 128 + t];
  red[t] = v;
  __syncthreads();
  for (int s = 64; s > 0; s >>= 1) { if (t < s) red[t] += red[t + s]; __syncthreads(); }
  float mean = red[0] / 128.0f;
  __syncthreads();
  float d = v - mean;
  red[t] = d * d;
  __syncthreads();
  for (int s = 64; s > 0; s >>= 1) { if (t < s) red[t] += red[t + s]; __syncthreads(); }
  float var = red[0] / 128.0f;
  xn[(size_t)node * 128 + t] = d * rsqrtf(var + EPSV) * g[t] + be[t];
}

// ---------------- neighbor-mean aggregation + degree ---------------------------
__global__ void aggregate_kernel(const u32* __restrict__ adj, const float* __restrict__ xn,
                                 float* __restrict__ m, float* __restrict__ dinv, int Ni) {
  int i = blockIdx.x, b = blockIdx.y, t = threadIdx.x;
  __shared__ int cnt;
  extern __shared__ int list[];
  if (t == 0) cnt = 0;
  __syncthreads();
  int wpr = Ni >> 5;
  for (int w = t; w < wpr; w += blockDim.x) {
    u32 bits = adj[((size_t)(b * Nmax + i)) * 64 + w];
    while (bits) {
      int bit = __ffs(bits) - 1;
      bits &= bits - 1;
      int pos = atomicAdd(&cnt, 1);
      list[pos] = (w << 5) + bit;
    }
  }
  __syncthreads();
  int d = cnt;
  float acc = 0.0f;
  for (int k = 0; k < d; ++k) acc += xn[((size_t)b * Ni + list[k]) * 128 + t];
  m[((size_t)b * Ni + i) * 128 + t] = acc / (float)d;
  if (t == 0) dinv[b * Nmax + i] = 1.0f / sqrtf((float)d);
}

// ---------------- generic fp32 GEMM: C = f((A@W [+ A2@W2]) * scale + bias) -----
__global__ __launch_bounds__(256) void gemm_kernel(
    const float* __restrict__ A, const float* __restrict__ W,
    const float* __restrict__ A2, const float* __restrict__ W2,
    const float* __restrict__ scale, const float* __restrict__ bias,
    float* __restrict__ C, int M, int N, int K, int flags) {
  __shared__ float As[16][65];
  __shared__ float Bs[16][65];
  int tx = threadIdx.x & 15, ty = threadIdx.x >> 4;
  int colBase = blockIdx.x * 64, rowBase = blockIdx.y * 64;
  float acc[4][4] = {};
  int npass = A2 ? 2 : 1;
  for (int pass = 0; pass < npass; ++pass) {
    const float* Ap = pass ? A2 : A;
    const float* Wp = pass ? W2 : W;
    for (int k0 = 0; k0 < K; k0 += 16) {
      for (int tdx = threadIdx.x; tdx < 64 * 16; tdx += 256) {
        int r = tdx >> 4, kk = tdx & 15;
        As[kk][r] = Ap[(size_t)(rowBase + r) * K + k0 + kk];
      }
      for (int tdx = threadIdx.x; tdx < 16 * 64; tdx += 256) {
        int kk = tdx >> 6, cc = tdx & 63;
        Bs[kk][cc] = Wp[(size_t)(k0 + kk) * N + colBase + cc];
      }
      __syncthreads();
#pragma unroll
      for (int kk = 0; kk < 16; ++kk) {
        float a[4], bv[4];
#pragma unroll
        for (int r = 0; r < 4; ++r) a[r] = As[kk][ty * 4 + r];
#pragma unroll
        for (int c = 0; c < 4; ++c) bv[c] = Bs[kk][tx * 4 + c];
#pragma unroll
        for (int r = 0; r < 4; ++r)
#pragma unroll
          for (int c = 0; c < 4; ++c) acc[r][c] += a[r] * bv[c];
      }
      __syncthreads();
    }
  }
#pragma unroll
  for (int r = 0; r < 4; ++r) {
    int row = rowBase + ty * 4 + r;
#pragma unroll
    for (int c = 0; c < 4; ++c) {
      int col = colBase + tx * 4 + c;
      float v = acc[r][c];
      if (scale) v *= scale[col];
      if (bias) v += bias[col];
      if (flags & GF_RELU) v = fmaxf(v, 0.0f);
      size_t o = (size_t)row * N + col;
      if (flags & GF_ACCUM) C[o] += v;
      else C[o] = v;
    }
  }
}

// ---------------- q = x@Wq ; p = dinv*q ---------------------------------------
__global__ void qp_kernel(const float* __restrict__ x, const float* __restrict__ Wq,
                          const float* __restrict__ dinv, float* __restrict__ p, int Ni) {
  int node = blockIdx.x;
  int lane = threadIdx.x;
  int b = node / Ni, i = node % Ni;
  float v = x[(size_t)node * 128 + lane] * Wq[lane] +
            x[(size_t)node * 128 + 64 + lane] * Wq[64 + lane];
  for (int off = 32; off >= 1; off >>= 1) v += __shfl_xor(v, off, 64);
  if (lane == 0) p[b * Nmax + i] = dinv[b * Nmax + i] * v;
}

// ---------------- s = dinv * (A @ p) + bq -------------------------------------
__global__ void score_kernel(const u32* __restrict__ adj, const float* __restrict__ p,
                             const float* __restrict__ dinv, const float* __restrict__ bq,
                             float* __restrict__ s, int Ni) {
  int i = blockIdx.x, b = blockIdx.y, lane = threadIdx.x;
  int wpr = Ni >> 5;
  float acc = 0.0f;
  if (lane < wpr) {
    u32 bits = adj[((size_t)(b * Nmax + i)) * 64 + lane];
    while (bits) {
      int bit = __ffs(bits) - 1;
      bits &= bits - 1;
      acc += p[b * Nmax + (lane << 5) + bit];
    }
  }
  for (int off = 32; off >= 1; off >>= 1) acc += __shfl_xor(acc, off, 64);
  if (lane == 0) s[b * Nmax + i] = dinv[b * Nmax + i] * acc + bq[0];
}

// ---------------- top-k via bitonic sort (desc value, asc index) ---------------
__global__ void topk_kernel(const float* __restrict__ s, int Ni, int* __restrict__ topi) {
  int b = blockIdx.x;
  int t = threadIdx.x;
  int T = blockDim.x;
  extern __shared__ u64 keys[];
  for (int e = t; e < Ni; e += T) {
    u32 u = __float_as_uint(s[b * Nmax + e]);
    u32 mono = (u & 0x80000000u) ? ~u : (u | 0x80000000u);
    keys[e] = ((u64)(~mono) << 32) | (u32)e;
  }
  __syncthreads();
  for (int kk = 2; kk <= Ni; kk <<= 1) {
    for (int j = kk >> 1; j > 0; j >>= 1) {
      for (int e = t; e < Ni; e += T) {
        int ixj = e ^ j;
        if (ixj > e) {
          u64 a = keys[e], b2 = keys[ixj];
          bool up = ((e & kk) == 0);
          if (up ? (a > b2) : (a < b2)) { keys[e] = b2; keys[ixj] = a; }
        }
      }
      __syncthreads();
    }
  }
  int kkeep = Ni >> 1;
  for (int e = t; e < kkeep; e += T) topi[b * 1024 + e] = (int)(keys[e] & 0xffffffffULL);
}

// ---------------- gather + tanh gate ------------------------------------------
__global__ void gather_kernel(const float* __restrict__ x, const float* __restrict__ c,
                              const float* __restrict__ s, const int* __restrict__ topi,
                              float* __restrict__ xo, float* __restrict__ co, int Ni) {
  int inew = blockIdx.x, b = blockIdx.y, t = threadIdx.x;
  int kkeep = Ni >> 1;
  int old = topi[b * 1024 + inew];
  float gate = tanhf(s[b * Nmax + old]);
  xo[((size_t)b * kkeep + inew) * 128 + t] = x[((size_t)b * Ni + old) * 128 + t] * gate;
  if (t < 2) co[((size_t)b * kkeep + inew) * 2 + t] = c[((size_t)b * Ni + old) * 2 + t];
}

// ---------------- picks: two-stage [max ; mean] reduction ----------------------
// stage 1: each block reduces a 32-row slice -> partial max/sum per feature
__global__ void picks_partial_kernel(const float* __restrict__ x, float* __restrict__ part,
                                     int kkeep, int G) {
  int b = blockIdx.x, g = blockIdx.y, t = threadIdx.x;
  int per = kkeep / G;                 // kkeep is a power of two, G divides it
  int start = g * per;
  float mx = -INFINITY, sm = 0.0f;
  for (int i = start; i < start + per; ++i) {
    float v = x[((size_t)b * kkeep + i) * 128 + t];
    mx = fmaxf(mx, v);
    sm += v;
  }
  part[((size_t)(b * G + g)) * 256 + t] = mx;
  part[((size_t)(b * G + g)) * 256 + 128 + t] = sm;
}

// stage 2: combine G partials, picks += [max ; mean]
__global__ void picks_combine_kernel(const float* __restrict__ part, float* __restrict__ picks,
                                     int kkeep, int G) {
  int b = blockIdx.x, t = threadIdx.x;
  float mx = -INFINITY, sm = 0.0f;
  for (int g = 0; g < G; ++g) {
    mx = fmaxf(mx, part[((size_t)(b * G + g)) * 256 + t]);
    sm += part[((size_t)(b * G + g)) * 256 + 128 + t];
  }
  picks[b * 256 + t] += mx;
  picks[b * 256 + 128 + t] += sm / (float)kkeep;
}

// ---------------- final 2-layer MLP -------------------------------------------
__global__ void final_kernel(const float* __restrict__ picks, const float* __restrict__ Wf1,
                             const float* __restrict__ bf1, const float* __restrict__ Wf2,
                             const float* __restrict__ bf2, float* __restrict__ out) {
  int b = blockIdx.x, t = threadIdx.x;
  __shared__ float pk[256];
  __shared__ float fm[128];
  pk[t] = picks[b * 256 + t];
  pk[t + 128] = picks[b * 256 + 128 + t];
  __syncthreads();
  float acc = bf1[t];
  for (int k = 0; k < 256; ++k) acc += pk[k] * Wf1[k * 128 + t];
  fm[t] = fmaxf(acc, 0.0f);
  __syncthreads();
  if (t < 32) {
    float a2 = bf2[t];
    for (int k = 0; k < 128; ++k) a2 += fm[k] * Wf2[k * 32 + t];
    out[b * 32 + t] = fmaxf(a2, 0.0f);
  }
}

extern "C" void kernel_launch(void* const* d_in, const int* in_sizes, int n_in,
                              void* d_out, int out_size, void* d_ws, size_t ws_size,
                              hipStream_t stream) {
  const float* feats = (const float*)d_in[0];
  const float* cent  = (const float*)d_in[1];
  const float* Wp1 = (const float*)d_in[2];
  const float* bp1 = (const float*)d_in[3];
  const float* bn_g = (const float*)d_in[4];
  const float* bn_b = (const float*)d_in[5];
  const float* Wp2 = (const float*)d_in[6];
  const float* bp2 = (const float*)d_in[7];
  const float* g1  = (const float*)d_in[8];
  const float* be1 = (const float*)d_in[9];
  const float* g2  = (const float*)d_in[10];
  const float* be2 = (const float*)d_in[11];
  const float* Ws  = (const float*)d_in[12];
  const float* Wn  = (const float*)d_in[13];
  const float* bs  = (const float*)d_in[14];
  const float* Wg  = (const float*)d_in[15];
  const float* bg  = (const float*)d_in[16];
  const float* W1  = (const float*)d_in[17];
  const float* b1  = (const float*)d_in[18];
  const float* W2  = (const float*)d_in[19];
  const float* b2  = (const float*)d_in[20];
  const float* Wq  = (const float*)d_in[21];
  const float* bq  = (const float*)d_in[22];
  const float* Wf1 = (const float*)d_in[23];
  const float* bf1 = (const float*)d_in[24];
  const float* Wf2 = (const float*)d_in[25];
  const float* bf2 = (const float*)d_in[26];
  float* out = (float*)d_out;

  float* ws = (float*)d_ws;
  const size_t SZX = (size_t)Bn * Nmax * 128;
  float* X0 = ws;    ws += SZX;
  float* X1 = ws;    ws += SZX;
  float* BA = ws;    ws += SZX;   // xn / xn2
  float* BB = ws;    ws += SZX;   // m / ffn tmp
  float* HB = ws;    ws += SZX;   // per-head h
  float* C0 = ws;    ws += (size_t)Bn * Nmax * 2;
  float* C1 = ws;    ws += (size_t)Bn * Nmax * 2;
  float* SC = ws;    ws += 128;
  float* BBv = ws;   ws += 128;
  float* DINV = ws;  ws += Bn * Nmax;
  float* PV = ws;    ws += Bn * Nmax;
  float* SS = ws;    ws += Bn * Nmax;
  float* PICKS = ws; ws += Bn * 256;
  float* PART = ws;  ws += (size_t)Bn * 32 * 256;  // picks partials (G<=32)
  int* KNN = (int*)ws;  ws += (size_t)Bn * Nmax * KNN_K;
  int* TOPI = (int*)ws; ws += Bn * 1024;
  u32* ADJ = (u32*)ws;  // Bn * Nmax * 64 u32

  hipLaunchKernelGGL(precompute_kernel, dim3(1), dim3(256), 0, stream,
                     bn_g, bn_b, bp1, SC, BBv, PICKS);

  // ---- preconv ----
  const int M0 = Bn * Nmax;
  hipLaunchKernelGGL(gemm_kernel, dim3(2, M0 / 64), dim3(256), 0, stream,
                     feats, Wp1, (const float*)nullptr, (const float*)nullptr,
                     SC, BBv, BA, M0, 128, 512, GF_RELU);
  hipLaunchKernelGGL(gemm_kernel, dim3(2, M0 / 64), dim3(256), 0, stream,
                     BA, Wp2, (const float*)nullptr, (const float*)nullptr,
                     (const float*)nullptr, bp2, X0, M0, 128, 128, 0);

  float* xc = X0;
  float* xo = X1;
  const float* cc = cent;
  float* co = C0;
  int Ni = Nmax;
  for (int L = 0; L < 3; ++L) {
    int M = Bn * Ni;
    hipLaunchKernelGGL(knn_kernel, dim3(Ni, Bn), dim3(64), 0, stream, cc, Ni, KNN);
    hipMemsetAsync(ADJ, 0, (size_t)Bn * Nmax * 64 * sizeof(u32), stream);
    int tot = Bn * Ni * KNN_K;
    hipLaunchKernelGGL(build_adj_kernel, dim3((tot + 255) / 256), dim3(256), 0, stream,
                       KNN, ADJ, Ni);
    hipLaunchKernelGGL(layernorm_kernel, dim3(M), dim3(128), 0, stream,
                       xc, g1 + L * 128, be1 + L * 128, BA);
    hipLaunchKernelGGL(aggregate_kernel, dim3(Ni, Bn), dim3(128), Ni * sizeof(int), stream,
                       ADJ, BA, BB, DINV, Ni);
    for (int hh = 0; hh < 4; ++hh) {
      hipLaunchKernelGGL(gemm_kernel, dim3(2, M / 64), dim3(256), 0, stream,
                         BA, Ws + ((size_t)(L * 4 + hh)) * 128 * 128,
                         BB, Wn + ((size_t)(L * 4 + hh)) * 128 * 128,
                         (const float*)nullptr, bs + (L * 4 + hh) * 128,
                         HB, M, 128, 128, GF_RELU);
      hipLaunchKernelGGL(gemm_kernel, dim3(2, M / 64), dim3(256), 0, stream,
                         HB, Wg + ((size_t)L * 512 + hh * 128) * 128,
                         (const float*)nullptr, (const float*)nullptr,
                         (const float*)nullptr, (hh == 0) ? (bg + L * 128) : (const float*)nullptr,
                         xc, M, 128, 128, GF_ACCUM);
    }
    hipLaunchKernelGGL(layernorm_kernel, dim3(M), dim3(128), 0, stream,
                       xc, g2 + L * 128, be2 + L * 128, BA);
    hipLaunchKernelGGL(gemm_kernel, dim3(2, M / 64), dim3(256), 0, stream,
                       BA, W1 + (size_t)L * 128 * 128, (const float*)nullptr, (const float*)nullptr,
                       (const float*)nullptr, b1 + L * 128, BB, M, 128, 128, GF_RELU);
    hipLaunchKernelGGL(gemm_kernel, dim3(2, M / 64), dim3(256), 0, stream,
                       BB, W2 + (size_t)L * 128 * 128, (const float*)nullptr, (const float*)nullptr,
                       (const float*)nullptr, b2 + L * 128, xc, M, 128, 128, GF_ACCUM);
    hipLaunchKernelGGL(qp_kernel, dim3(M), dim3(64), 0, stream, xc, Wq + L * 128, DINV, PV, Ni);
    hipLaunchKernelGGL(score_kernel, dim3(Ni, Bn), dim3(64), 0, stream, ADJ, PV, DINV, bq + L, SS, Ni);
    hipLaunchKernelGGL(topk_kernel, dim3(Bn), dim3(1024), Ni * sizeof(u64), stream, SS, Ni, TOPI);
    int kkeep = Ni >> 1;
    hipLaunchKernelGGL(gather_kernel, dim3(kkeep, Bn), dim3(128), 0, stream,
                       xc, cc, SS, TOPI, xo, co, Ni);
    int G = kkeep / 32;               // 32 rows per partial block
    hipLaunchKernelGGL(picks_partial_kernel, dim3(Bn, G), dim3(128), 0, stream,
                       xo, PART, kkeep, G);
    hipLaunchKernelGGL(picks_combine_kernel, dim3(Bn), dim3(128), 0, stream,
                       PART, PICKS, kkeep, G);
    float* tmp = xc; xc = xo; xo = tmp;
    cc = co;
    co = (co == C0) ? C1 : C0;
    Ni = kkeep;
  }
  hipLaunchKernelGGL(final_kernel, dim3(Bn), dim3(128), 0, stream,
                     PICKS, Wf1, bf1, Wf2, bf2, out);
}

// Round 3
// 1154.381 us; speedup vs baseline: 1.6993x; 1.3501x over previous
//
#include <hip/hip_runtime.h>
#include <math.h>

#define EPSV 1e-5f
#define GF_RELU 1
#define GF_ACCUM 2

typedef unsigned long long u64;
typedef unsigned int u32;

static const int Bn = 8;
static const int Nmax = 2048;
static const int KNN_K = 8;

// ---------------- precompute: fold BN into scale/bias, zero picks ----------------
__global__ void precompute_kernel(const float* __restrict__ bn_g, const float* __restrict__ bn_b,
                                  const float* __restrict__ bp1,
                                  float* __restrict__ sc, float* __restrict__ bb,
                                  float* __restrict__ picks) {
  int t = threadIdx.x;
  if (t < 128) {
    float s = bn_g[t] / sqrtf(1.0f + EPSV);
    sc[t] = s;
    bb[t] = bp1[t] * s + bn_b[t];
  }
  for (int i = t; i < Bn * 256; i += blockDim.x) picks[i] = 0.0f;
}

// ---------------- KNN: one wave per node, exact (d2,idx) lexicographic top-8 ----
__global__ void knn_kernel(const float* __restrict__ cent, int Ni, int* __restrict__ knn_idx) {
  int i = blockIdx.x, b = blockIdx.y, lane = threadIdx.x;
  const float* cb = cent + (size_t)b * Ni * 2;
  float xi = cb[2 * i], yi = cb[2 * i + 1];
  u64 best[8];
#pragma unroll
  for (int t = 0; t < 8; ++t) best[t] = ~0ULL;
  for (int j = lane; j < Ni; j += 64) {
    float dx = __fsub_rn(xi, cb[2 * j]);
    float dy = __fsub_rn(yi, cb[2 * j + 1]);
    float d2 = __fadd_rn(__fmul_rn(dx, dx), __fmul_rn(dy, dy));
    u64 key = ((u64)__float_as_uint(d2) << 32) | (u32)j;
    if (key < best[7]) {
      best[7] = key;
      for (int t = 7; t > 0; --t) {
        if (best[t] < best[t - 1]) { u64 tmp = best[t - 1]; best[t - 1] = best[t]; best[t] = tmp; }
        else break;
      }
    }
  }
  int ptr = 0;
  for (int r = 0; r < KNN_K; ++r) {
    u64 mine = (ptr < 8) ? best[ptr] : ~0ULL;
    u64 mn = mine;
    for (int off = 32; off >= 1; off >>= 1) {
      u64 o = __shfl_xor(mn, off, 64);
      if (o < mn) mn = o;
    }
    if (mine == mn) ptr++;
    if (lane == 0) knn_idx[((size_t)(b * Ni + i)) * KNN_K + r] = (int)(mn & 0xffffffffULL);
  }
}

// ---------------- adjacency bitmask: A = mask | mask^T -------------------------
__global__ void build_adj_kernel(const int* __restrict__ knn_idx, u32* __restrict__ adj, int Ni) {
  int e = blockIdx.x * blockDim.x + threadIdx.x;
  int total = Bn * Ni * KNN_K;
  if (e >= total) return;
  int b = e / (Ni * KNN_K);
  int rem = e % (Ni * KNN_K);
  int r = rem / KNN_K;
  int j = knn_idx[e];
  atomicOr(&adj[((size_t)(b * Nmax + r)) * 64 + (j >> 5)], 1u << (j & 31));
  atomicOr(&adj[((size_t)(b * Nmax + j)) * 64 + (r >> 5)], 1u << (r & 31));
}

// ---------------- layernorm over H=128, one block per node ---------------------
__global__ void layernorm_kernel(const float* __restrict__ x, const float* __restrict__ g,
                                 const float* __restrict__ be, float* __restrict__ xn) {
  int node = blockIdx.x;
  int t = threadIdx.x;
  __shared__ float red[128];
  float v = x[(size_t)node * 128 + t];
  red[t] = v;
  __syncthreads();
  for (int s = 64; s > 0; s >>= 1) { if (t < s) red[t] += red[t + s]; __syncthreads(); }
  float mean = red[0] / 128.0f;
  __syncthreads();
  float d = v - mean;
  red[t] = d * d;
  __syncthreads();
  for (int s = 64; s > 0; s >>= 1) { if (t < s) red[t] += red[t + s]; __syncthreads(); }
  float var = red[0] / 128.0f;
  xn[(size_t)node * 128 + t] = d * rsqrtf(var + EPSV) * g[t] + be[t];
}

// ---------------- neighbor-mean aggregation + degree ---------------------------
__global__ void aggregate_kernel(const u32* __restrict__ adj, const float* __restrict__ xn,
                                 float* __restrict__ m, float* __restrict__ dinv, int Ni) {
  int i = blockIdx.x, b = blockIdx.y, t = threadIdx.x;
  __shared__ int cnt;
  extern __shared__ int list[];
  if (t == 0) cnt = 0;
  __syncthreads();
  int wpr = Ni >> 5;
  for (int w = t; w < wpr; w += blockDim.x) {
    u32 bits = adj[((size_t)(b * Nmax + i)) * 64 + w];
    while (bits) {
      int bit = __ffs(bits) - 1;
      bits &= bits - 1;
      int pos = atomicAdd(&cnt, 1);
      list[pos] = (w << 5) + bit;
    }
  }
  __syncthreads();
  int d = cnt;
  float acc = 0.0f;
  for (int k = 0; k < d; ++k) acc += xn[((size_t)b * Ni + list[k]) * 128 + t];
  m[((size_t)b * Ni + i) * 128 + t] = acc / (float)d;
  if (t == 0) dinv[b * Nmax + i] = 1.0f / sqrtf((float)d);
}

// ---------------- fp32 GEMM: C = f((A@W [+ A2@W2]) * scale + bias) -------------
// tile: 64 rows x 128 cols, 256 threads, 8x4 acc/thread, K-step 16.
// Requires: M % 64 == 0, N % 128 == 0, K % 16 == 0. grid = (N/128, M/64).
__global__ __launch_bounds__(256) void gemm_kernel(
    const float* __restrict__ A, const float* __restrict__ W,
    const float* __restrict__ A2, const float* __restrict__ W2,
    const float* __restrict__ scale, const float* __restrict__ bias,
    float* __restrict__ C, int M, int N, int K, int flags) {
  __shared__ float As[16][68];
  __shared__ float Bs[16][132];
  int tid = threadIdx.x;
  int tx = tid & 31;        // 4 cols each
  int ty = tid >> 5;        // 8 rows each
  int colBase = blockIdx.x * 128, rowBase = blockIdx.y * 64;
  float acc[8][4] = {};
  int npass = A2 ? 2 : 1;
  for (int pass = 0; pass < npass; ++pass) {
    const float* Ap = pass ? A2 : A;
    const float* Wp = pass ? W2 : W;
    for (int k0 = 0; k0 < K; k0 += 16) {
      // stage A: 64 rows x 16 k, one float4 per thread
      {
        int row = tid >> 2, q = (tid & 3) * 4;
        float4 v = *(const float4*)(Ap + (size_t)(rowBase + row) * K + k0 + q);
        As[q + 0][row] = v.x;
        As[q + 1][row] = v.y;
        As[q + 2][row] = v.z;
        As[q + 3][row] = v.w;
      }
      // stage B: 16 k x 128 cols, two float4 per thread
      {
        int kk = tid >> 5, cc = (tid & 31) * 4;
        *(float4*)&Bs[kk][cc] = *(const float4*)(Wp + (size_t)(k0 + kk) * N + colBase + cc);
        *(float4*)&Bs[kk + 8][cc] = *(const float4*)(Wp + (size_t)(k0 + kk + 8) * N + colBase + cc);
      }
      __syncthreads();
#pragma unroll
      for (int kk = 0; kk < 16; ++kk) {
        float a[8], bv[4];
        *(float4*)&a[0] = *(const float4*)&As[kk][ty * 8];
        *(float4*)&a[4] = *(const float4*)&As[kk][ty * 8 + 4];
        *(float4*)&bv[0] = *(const float4*)&Bs[kk][tx * 4];
#pragma unroll
        for (int r = 0; r < 8; ++r)
#pragma unroll
          for (int c = 0; c < 4; ++c) acc[r][c] += a[r] * bv[c];
      }
      __syncthreads();
    }
  }
#pragma unroll
  for (int r = 0; r < 8; ++r) {
    int row = rowBase + ty * 8 + r;
    int col = colBase + tx * 4;
    float4 v;
    float* vp = (float*)&v;
#pragma unroll
    for (int c = 0; c < 4; ++c) {
      float t = acc[r][c];
      if (scale) t *= scale[col + c];
      if (bias) t += bias[col + c];
      if (flags & GF_RELU) t = fmaxf(t, 0.0f);
      vp[c] = t;
    }
    size_t o = (size_t)row * N + col;
    if (flags & GF_ACCUM) {
      float4 old = *(float4*)&C[o];
      v.x += old.x; v.y += old.y; v.z += old.z; v.w += old.w;
    }
    *(float4*)&C[o] = v;
  }
}

// ---------------- q = x@Wq ; p = dinv*q ---------------------------------------
__global__ void qp_kernel(const float* __restrict__ x, const float* __restrict__ Wq,
                          const float* __restrict__ dinv, float* __restrict__ p, int Ni) {
  int node = blockIdx.x;
  int lane = threadIdx.x;
  int b = node / Ni, i = node % Ni;
  float v = x[(size_t)node * 128 + lane] * Wq[lane] +
            x[(size_t)node * 128 + 64 + lane] * Wq[64 + lane];
  for (int off = 32; off >= 1; off >>= 1) v += __shfl_xor(v, off, 64);
  if (lane == 0) p[b * Nmax + i] = dinv[b * Nmax + i] * v;
}

// ---------------- s = dinv * (A @ p) + bq -------------------------------------
__global__ void score_kernel(const u32* __restrict__ adj, const float* __restrict__ p,
                             const float* __restrict__ dinv, const float* __restrict__ bq,
                             float* __restrict__ s, int Ni) {
  int i = blockIdx.x, b = blockIdx.y, lane = threadIdx.x;
  int wpr = Ni >> 5;
  float acc = 0.0f;
  if (lane < wpr) {
    u32 bits = adj[((size_t)(b * Nmax + i)) * 64 + lane];
    while (bits) {
      int bit = __ffs(bits) - 1;
      bits &= bits - 1;
      acc += p[b * Nmax + (lane << 5) + bit];
    }
  }
  for (int off = 32; off >= 1; off >>= 1) acc += __shfl_xor(acc, off, 64);
  if (lane == 0) s[b * Nmax + i] = dinv[b * Nmax + i] * acc + bq[0];
}

// ---------------- top-k via bitonic sort (desc value, asc index) ---------------
__global__ void topk_kernel(const float* __restrict__ s, int Ni, int* __restrict__ topi) {
  int b = blockIdx.x;
  int t = threadIdx.x;
  int T = blockDim.x;
  extern __shared__ u64 keys[];
  for (int e = t; e < Ni; e += T) {
    u32 u = __float_as_uint(s[b * Nmax + e]);
    u32 mono = (u & 0x80000000u) ? ~u : (u | 0x80000000u);
    keys[e] = ((u64)(~mono) << 32) | (u32)e;
  }
  __syncthreads();
  for (int kk = 2; kk <= Ni; kk <<= 1) {
    for (int j = kk >> 1; j > 0; j >>= 1) {
      for (int e = t; e < Ni; e += T) {
        int ixj = e ^ j;
        if (ixj > e) {
          u64 a = keys[e], b2 = keys[ixj];
          bool up = ((e & kk) == 0);
          if (up ? (a > b2) : (a < b2)) { keys[e] = b2; keys[ixj] = a; }
        }
      }
      __syncthreads();
    }
  }
  int kkeep = Ni >> 1;
  for (int e = t; e < kkeep; e += T) topi[b * 1024 + e] = (int)(keys[e] & 0xffffffffULL);
}

// ---------------- gather + tanh gate ------------------------------------------
__global__ void gather_kernel(const float* __restrict__ x, const float* __restrict__ c,
                              const float* __restrict__ s, const int* __restrict__ topi,
                              float* __restrict__ xo, float* __restrict__ co, int Ni) {
  int inew = blockIdx.x, b = blockIdx.y, t = threadIdx.x;
  int kkeep = Ni >> 1;
  int old = topi[b * 1024 + inew];
  float gate = tanhf(s[b * Nmax + old]);
  xo[((size_t)b * kkeep + inew) * 128 + t] = x[((size_t)b * Ni + old) * 128 + t] * gate;
  if (t < 2) co[((size_t)b * kkeep + inew) * 2 + t] = c[((size_t)b * Ni + old) * 2 + t];
}

// ---------------- picks: two-stage [max ; mean] reduction ----------------------
__global__ void picks_partial_kernel(const float* __restrict__ x, float* __restrict__ part,
                                     int kkeep, int G) {
  int b = blockIdx.x, g = blockIdx.y, t = threadIdx.x;
  int per = kkeep / G;
  int start = g * per;
  float mx = -INFINITY, sm = 0.0f;
  for (int i = start; i < start + per; ++i) {
    float v = x[((size_t)b * kkeep + i) * 128 + t];
    mx = fmaxf(mx, v);
    sm += v;
  }
  part[((size_t)(b * G + g)) * 256 + t] = mx;
  part[((size_t)(b * G + g)) * 256 + 128 + t] = sm;
}

__global__ void picks_combine_kernel(const float* __restrict__ part, float* __restrict__ picks,
                                     int kkeep, int G) {
  int b = blockIdx.x, t = threadIdx.x;
  float mx = -INFINITY, sm = 0.0f;
  for (int g = 0; g < G; ++g) {
    mx = fmaxf(mx, part[((size_t)(b * G + g)) * 256 + t]);
    sm += part[((size_t)(b * G + g)) * 256 + 128 + t];
  }
  picks[b * 256 + t] += mx;
  picks[b * 256 + 128 + t] += sm / (float)kkeep;
}

// ---------------- final 2-layer MLP -------------------------------------------
__global__ void final_kernel(const float* __restrict__ picks, const float* __restrict__ Wf1,
                             const float* __restrict__ bf1, const float* __restrict__ Wf2,
                             const float* __restrict__ bf2, float* __restrict__ out) {
  int b = blockIdx.x, t = threadIdx.x;
  __shared__ float pk[256];
  __shared__ float fm[128];
  pk[t] = picks[b * 256 + t];
  pk[t + 128] = picks[b * 256 + 128 + t];
  __syncthreads();
  float acc = bf1[t];
  for (int k = 0; k < 256; ++k) acc += pk[k] * Wf1[k * 128 + t];
  fm[t] = fmaxf(acc, 0.0f);
  __syncthreads();
  if (t < 32) {
    float a2 = bf2[t];
    for (int k = 0; k < 128; ++k) a2 += fm[k] * Wf2[k * 32 + t];
    out[b * 32 + t] = fmaxf(a2, 0.0f);
  }
}

extern "C" void kernel_launch(void* const* d_in, const int* in_sizes, int n_in,
                              void* d_out, int out_size, void* d_ws, size_t ws_size,
                              hipStream_t stream) {
  const float* feats = (const float*)d_in[0];
  const float* cent  = (const float*)d_in[1];
  const float* Wp1 = (const float*)d_in[2];
  const float* bp1 = (const float*)d_in[3];
  const float* bn_g = (const float*)d_in[4];
  const float* bn_b = (const float*)d_in[5];
  const float* Wp2 = (const float*)d_in[6];
  const float* bp2 = (const float*)d_in[7];
  const float* g1  = (const float*)d_in[8];
  const float* be1 = (const float*)d_in[9];
  const float* g2  = (const float*)d_in[10];
  const float* be2 = (const float*)d_in[11];
  const float* Ws  = (const float*)d_in[12];
  const float* Wn  = (const float*)d_in[13];
  const float* bs  = (const float*)d_in[14];
  const float* Wg  = (const float*)d_in[15];
  const float* bg  = (const float*)d_in[16];
  const float* W1  = (const float*)d_in[17];
  const float* b1  = (const float*)d_in[18];
  const float* W2  = (const float*)d_in[19];
  const float* b2  = (const float*)d_in[20];
  const float* Wq  = (const float*)d_in[21];
  const float* bq  = (const float*)d_in[22];
  const float* Wf1 = (const float*)d_in[23];
  const float* bf1 = (const float*)d_in[24];
  const float* Wf2 = (const float*)d_in[25];
  const float* bf2 = (const float*)d_in[26];
  float* out = (float*)d_out;

  float* ws = (float*)d_ws;
  const size_t SZX = (size_t)Bn * Nmax * 128;
  float* X0 = ws;    ws += SZX;
  float* X1 = ws;    ws += SZX;
  float* BA = ws;    ws += SZX;   // xn / xn2
  float* BB = ws;    ws += SZX;   // m / ffn tmp
  float* HB = ws;    ws += SZX;   // per-head h
  float* C0 = ws;    ws += (size_t)Bn * Nmax * 2;
  float* C1 = ws;    ws += (size_t)Bn * Nmax * 2;
  float* SC = ws;    ws += 128;
  float* BBv = ws;   ws += 128;
  float* DINV = ws;  ws += Bn * Nmax;
  float* PV = ws;    ws += Bn * Nmax;
  float* SS = ws;    ws += Bn * Nmax;
  float* PICKS = ws; ws += Bn * 256;
  float* PART = ws;  ws += (size_t)Bn * 32 * 256;
  int* KNN = (int*)ws;  ws += (size_t)Bn * Nmax * KNN_K;
  int* TOPI = (int*)ws; ws += Bn * 1024;
  u32* ADJ = (u32*)ws;  // Bn * Nmax * 64 u32

  hipLaunchKernelGGL(precompute_kernel, dim3(1), dim3(256), 0, stream,
                     bn_g, bn_b, bp1, SC, BBv, PICKS);

  // ---- preconv ----
  const int M0 = Bn * Nmax;
  hipLaunchKernelGGL(gemm_kernel, dim3(1, M0 / 64), dim3(256), 0, stream,
                     feats, Wp1, (const float*)nullptr, (const float*)nullptr,
                     SC, BBv, BA, M0, 128, 512, GF_RELU);
  hipLaunchKernelGGL(gemm_kernel, dim3(1, M0 / 64), dim3(256), 0, stream,
                     BA, Wp2, (const float*)nullptr, (const float*)nullptr,
                     (const float*)nullptr, bp2, X0, M0, 128, 128, 0);

  float* xc = X0;
  float* xo = X1;
  const float* cc = cent;
  float* co = C0;
  int Ni = Nmax;
  for (int L = 0; L < 3; ++L) {
    int M = Bn * Ni;
    hipLaunchKernelGGL(knn_kernel, dim3(Ni, Bn), dim3(64), 0, stream, cc, Ni, KNN);
    hipMemsetAsync(ADJ, 0, (size_t)Bn * Nmax * 64 * sizeof(u32), stream);
    int tot = Bn * Ni * KNN_K;
    hipLaunchKernelGGL(build_adj_kernel, dim3((tot + 255) / 256), dim3(256), 0, stream,
                       KNN, ADJ, Ni);
    hipLaunchKernelGGL(layernorm_kernel, dim3(M), dim3(128), 0, stream,
                       xc, g1 + L * 128, be1 + L * 128, BA);
    hipLaunchKernelGGL(aggregate_kernel, dim3(Ni, Bn), dim3(128), Ni * sizeof(int), stream,
                       ADJ, BA, BB, DINV, Ni);
    for (int hh = 0; hh < 4; ++hh) {
      hipLaunchKernelGGL(gemm_kernel, dim3(1, M / 64), dim3(256), 0, stream,
                         BA, Ws + ((size_t)(L * 4 + hh)) * 128 * 128,
                         BB, Wn + ((size_t)(L * 4 + hh)) * 128 * 128,
                         (const float*)nullptr, bs + (L * 4 + hh) * 128,
                         HB, M, 128, 128, GF_RELU);
      hipLaunchKernelGGL(gemm_kernel, dim3(1, M / 64), dim3(256), 0, stream,
                         HB, Wg + ((size_t)L * 512 + hh * 128) * 128,
                         (const float*)nullptr, (const float*)nullptr,
                         (const float*)nullptr, (hh == 0) ? (bg + L * 128) : (const float*)nullptr,
                         xc, M, 128, 128, GF_ACCUM);
    }
    hipLaunchKernelGGL(layernorm_kernel, dim3(M), dim3(128), 0, stream,
                       xc, g2 + L * 128, be2 + L * 128, BA);
    hipLaunchKernelGGL(gemm_kernel, dim3(1, M / 64), dim3(256), 0, stream,
                       BA, W1 + (size_t)L * 128 * 128, (const float*)nullptr, (const float*)nullptr,
                       (const float*)nullptr, b1 + L * 128, BB, M, 128, 128, GF_RELU);
    hipLaunchKernelGGL(gemm_kernel, dim3(1, M / 64), dim3(256), 0, stream,
                       BB, W2 + (size_t)L * 128 * 128, (const float*)nullptr, (const float*)nullptr,
                       (const float*)nullptr, b2 + L * 128, xc, M, 128, 128, GF_ACCUM);
    hipLaunchKernelGGL(qp_kernel, dim3(M), dim3(64), 0, stream, xc, Wq + L * 128, DINV, PV, Ni);
    hipLaunchKernelGGL(score_kernel, dim3(Ni, Bn), dim3(64), 0, stream, ADJ, PV, DINV, bq + L, SS, Ni);
    hipLaunchKernelGGL(topk_kernel, dim3(Bn), dim3(1024), Ni * sizeof(u64), stream, SS, Ni, TOPI);
    int kkeep = Ni >> 1;
    hipLaunchKernelGGL(gather_kernel, dim3(kkeep, Bn), dim3(128), 0, stream,
                       xc, cc, SS, TOPI, xo, co, Ni);
    int G = kkeep / 32;
    hipLaunchKernelGGL(picks_partial_kernel, dim3(Bn, G), dim3(128), 0, stream,
                       xo, PART, kkeep, G);
    hipLaunchKernelGGL(picks_combine_kernel, dim3(Bn), dim3(128), 0, stream,
                       PART, PICKS, kkeep, G);
    float* tmp = xc; xc = xo; xo = tmp;
    cc = co;
    co = (co == C0) ? C1 : C0;
    Ni = kkeep;
  }
  hipLaunchKernelGGL(final_kernel, dim3(Bn), dim3(128), 0, stream,
                     PICKS, Wf1, bf1, Wf2, bf2, out);
}

// Round 4
// 887.511 us; speedup vs baseline: 2.2103x; 1.3007x over previous
//
#include <hip/hip_runtime.h>
#include <math.h>

#define EPSV 1e-5f
#define GF_RELU 1
#define GF_ACCUM 2

typedef unsigned long long u64;
typedef unsigned int u32;

static const int Bn = 8;
static const int Nmax = 2048;
static const int KNN_K = 8;

// ---------------- precompute: fold BN into scale/bias, zero picks ----------------
__global__ void precompute_kernel(const float* __restrict__ bn_g, const float* __restrict__ bn_b,
                                  const float* __restrict__ bp1,
                                  float* __restrict__ sc, float* __restrict__ bb,
                                  float* __restrict__ picks) {
  int t = threadIdx.x;
  if (t < 128) {
    float s = bn_g[t] / sqrtf(1.0f + EPSV);
    sc[t] = s;
    bb[t] = bp1[t] * s + bn_b[t];
  }
  for (int i = t; i < Bn * 256; i += blockDim.x) picks[i] = 0.0f;
}

// ---------------- repack Ws/Wn [L][h][d][e] -> [L][d][h*128+e] -----------------
__global__ void repack_ws_kernel(const float* __restrict__ Ws, const float* __restrict__ Wn,
                                 float* __restrict__ WsP, float* __restrict__ WnP) {
  int idx = blockIdx.x * 256 + threadIdx.x;
  const int total = 3 * 4 * 128 * 128;
  if (idx >= total) return;
  int e = idx & 127, d = (idx >> 7) & 127, h = (idx >> 14) & 3, L = idx >> 16;
  size_t dst = ((size_t)L * 128 + d) * 512 + h * 128 + e;
  WsP[dst] = Ws[idx];
  WnP[dst] = Wn[idx];
}

// ---------------- KNN: keys in registers, 8 wave-min extraction rounds ---------
template<int T>
__global__ __launch_bounds__(64) void knn_sel_kernel(const float* __restrict__ cent,
                                                     int* __restrict__ knn_idx, int Ni) {
  int i = blockIdx.x, b = blockIdx.y, lane = threadIdx.x;
  const float2* cb = (const float2*)(cent + (size_t)b * Ni * 2);
  float2 ci = cb[i];
  u64 keys[T];
#pragma unroll
  for (int t = 0; t < T; ++t) {
    int j = (t << 6) + lane;
    float2 cj = cb[j];
    float dx = __fsub_rn(ci.x, cj.x);
    float dy = __fsub_rn(ci.y, cj.y);
    float d2 = __fadd_rn(__fmul_rn(dx, dx), __fmul_rn(dy, dy));
    keys[t] = ((u64)__float_as_uint(d2) << 32) | (u32)j;
  }
  u64 prev = 0;
  for (int r = 0; r < KNN_K; ++r) {
    u64 best = ~0ULL;
    if (r == 0) {
#pragma unroll
      for (int t = 0; t < T; ++t) { if (keys[t] < best) best = keys[t]; }
    } else {
#pragma unroll
      for (int t = 0; t < T; ++t) { if (keys[t] > prev && keys[t] < best) best = keys[t]; }
    }
    for (int off = 32; off >= 1; off >>= 1) {
      u64 o = __shfl_xor(best, off, 64);
      if (o < best) best = o;
    }
    if (lane == 0) knn_idx[((size_t)(b * Ni + i)) * KNN_K + r] = (int)(best & 0xffffffffULL);
    prev = best;
  }
}

// ---------------- adjacency bitmask: A = mask | mask^T -------------------------
__global__ void build_adj_kernel(const int* __restrict__ knn_idx, u32* __restrict__ adj, int Ni) {
  int e = blockIdx.x * blockDim.x + threadIdx.x;
  int total = Bn * Ni * KNN_K;
  if (e >= total) return;
  int b = e / (Ni * KNN_K);
  int rem = e % (Ni * KNN_K);
  int r = rem / KNN_K;
  int j = knn_idx[e];
  atomicOr(&adj[((size_t)(b * Nmax + r)) * 64 + (j >> 5)], 1u << (j & 31));
  atomicOr(&adj[((size_t)(b * Nmax + j)) * 64 + (r >> 5)], 1u << (r & 31));
}

// ---------------- layernorm over H=128, one block per node ---------------------
__global__ void layernorm_kernel(const float* __restrict__ x, const float* __restrict__ g,
                                 const float* __restrict__ be, float* __restrict__ xn) {
  int node = blockIdx.x;
  int t = threadIdx.x;
  __shared__ float red[128];
  float v = x[(size_t)node * 128 + t];
  red[t] = v;
  __syncthreads();
  for (int s = 64; s > 0; s >>= 1) { if (t < s) red[t] += red[t + s]; __syncthreads(); }
  float mean = red[0] / 128.0f;
  __syncthreads();
  float d = v - mean;
  red[t] = d * d;
  __syncthreads();
  for (int s = 64; s > 0; s >>= 1) { if (t < s) red[t] += red[t + s]; __syncthreads(); }
  float var = red[0] / 128.0f;
  xn[(size_t)node * 128 + t] = d * rsqrtf(var + EPSV) * g[t] + be[t];
}

// ---------------- neighbor-mean aggregation + degree ---------------------------
__global__ void aggregate_kernel(const u32* __restrict__ adj, const float* __restrict__ xn,
                                 float* __restrict__ m, float* __restrict__ dinv, int Ni) {
  int i = blockIdx.x, b = blockIdx.y, t = threadIdx.x;
  __shared__ int cnt;
  extern __shared__ int list[];
  if (t == 0) cnt = 0;
  __syncthreads();
  int wpr = Ni >> 5;
  for (int w = t; w < wpr; w += blockDim.x) {
    u32 bits = adj[((size_t)(b * Nmax + i)) * 64 + w];
    while (bits) {
      int bit = __ffs(bits) - 1;
      bits &= bits - 1;
      int pos = atomicAdd(&cnt, 1);
      list[pos] = (w << 5) + bit;
    }
  }
  __syncthreads();
  int d = cnt;
  float acc = 0.0f;
  for (int k = 0; k < d; ++k) acc += xn[((size_t)b * Ni + list[k]) * 128 + t];
  m[((size_t)b * Ni + i) * 128 + t] = acc / (float)d;
  if (t == 0) dinv[b * Nmax + i] = 1.0f / sqrtf((float)d);
}

// ---------------- fp32 GEMM: C = f((A@W [+ A2@W2]) * scale + bias) -------------
// tile: 64 rows x 128 cols, 256 threads, 8x4 acc/thread, K-step 16.
// Requires: M % 64 == 0, N % 128 == 0, K % 16 == 0. grid = (N/128, M/64).
__global__ __launch_bounds__(256) void gemm_kernel(
    const float* __restrict__ A, const float* __restrict__ W,
    const float* __restrict__ A2, const float* __restrict__ W2,
    const float* __restrict__ scale, const float* __restrict__ bias,
    float* __restrict__ C, int M, int N, int K, int flags) {
  __shared__ float As[16][68];
  __shared__ float Bs[16][132];
  int tid = threadIdx.x;
  int tx = tid & 31;        // 4 cols each
  int ty = tid >> 5;        // 8 rows each
  int colBase = blockIdx.x * 128, rowBase = blockIdx.y * 64;
  float acc[8][4] = {};
  int npass = A2 ? 2 : 1;
  for (int pass = 0; pass < npass; ++pass) {
    const float* Ap = pass ? A2 : A;
    const float* Wp = pass ? W2 : W;
    for (int k0 = 0; k0 < K; k0 += 16) {
      {
        int row = tid >> 2, q = (tid & 3) * 4;
        float4 v = *(const float4*)(Ap + (size_t)(rowBase + row) * K + k0 + q);
        As[q + 0][row] = v.x;
        As[q + 1][row] = v.y;
        As[q + 2][row] = v.z;
        As[q + 3][row] = v.w;
      }
      {
        int kk = tid >> 5, cc = (tid & 31) * 4;
        *(float4*)&Bs[kk][cc] = *(const float4*)(Wp + (size_t)(k0 + kk) * N + colBase + cc);
        *(float4*)&Bs[kk + 8][cc] = *(const float4*)(Wp + (size_t)(k0 + kk + 8) * N + colBase + cc);
      }
      __syncthreads();
#pragma unroll
      for (int kk = 0; kk < 16; ++kk) {
        float a[8], bv[4];
        *(float4*)&a[0] = *(const float4*)&As[kk][ty * 8];
        *(float4*)&a[4] = *(const float4*)&As[kk][ty * 8 + 4];
        *(float4*)&bv[0] = *(const float4*)&Bs[kk][tx * 4];
#pragma unroll
        for (int r = 0; r < 8; ++r)
#pragma unroll
          for (int c = 0; c < 4; ++c) acc[r][c] += a[r] * bv[c];
      }
      __syncthreads();
    }
  }
#pragma unroll
  for (int r = 0; r < 8; ++r) {
    int row = rowBase + ty * 8 + r;
    int col = colBase + tx * 4;
    float4 v;
    float* vp = (float*)&v;
#pragma unroll
    for (int c = 0; c < 4; ++c) {
      float t = acc[r][c];
      if (scale) t *= scale[col + c];
      if (bias) t += bias[col + c];
      if (flags & GF_RELU) t = fmaxf(t, 0.0f);
      vp[c] = t;
    }
    size_t o = (size_t)row * N + col;
    if (flags & GF_ACCUM) {
      float4 old = *(float4*)&C[o];
      v.x += old.x; v.y += old.y; v.z += old.z; v.w += old.w;
    }
    *(float4*)&C[o] = v;
  }
}

// ---------------- q = x@Wq ; p = dinv*q ---------------------------------------
__global__ void qp_kernel(const float* __restrict__ x, const float* __restrict__ Wq,
                          const float* __restrict__ dinv, float* __restrict__ p, int Ni) {
  int node = blockIdx.x;
  int lane = threadIdx.x;
  int b = node / Ni, i = node % Ni;
  float v = x[(size_t)node * 128 + lane] * Wq[lane] +
            x[(size_t)node * 128 + 64 + lane] * Wq[64 + lane];
  for (int off = 32; off >= 1; off >>= 1) v += __shfl_xor(v, off, 64);
  if (lane == 0) p[b * Nmax + i] = dinv[b * Nmax + i] * v;
}

// ---------------- s = dinv * (A @ p) + bq -------------------------------------
__global__ void score_kernel(const u32* __restrict__ adj, const float* __restrict__ p,
                             const float* __restrict__ dinv, const float* __restrict__ bq,
                             float* __restrict__ s, int Ni) {
  int i = blockIdx.x, b = blockIdx.y, lane = threadIdx.x;
  int wpr = Ni >> 5;
  float acc = 0.0f;
  if (lane < wpr) {
    u32 bits = adj[((size_t)(b * Nmax + i)) * 64 + lane];
    while (bits) {
      int bit = __ffs(bits) - 1;
      bits &= bits - 1;
      acc += p[b * Nmax + (lane << 5) + bit];
    }
  }
  for (int off = 32; off >= 1; off >>= 1) acc += __shfl_xor(acc, off, 64);
  if (lane == 0) s[b * Nmax + i] = dinv[b * Nmax + i] * acc + bq[0];
}

// ---------------- top-k via exact rank counting --------------------------------
// keys unique (value||index); rank(e) = #{keys < key_e}; keep rank < Ni/2.
__global__ void topk_rank_kernel(const float* __restrict__ s, int Ni, int* __restrict__ topi) {
  int b = blockIdx.y;
  int e0 = blockIdx.x * 256;
  int t = threadIdx.x;
  __shared__ u64 keys[2048];
  for (int e = t; e < Ni; e += 256) {
    u32 u = __float_as_uint(s[b * Nmax + e]);
    u32 mono = (u & 0x80000000u) ? ~u : (u | 0x80000000u);
    keys[e] = ((u64)(~mono) << 32) | (u32)e;
  }
  __syncthreads();
  int e = e0 + t;
  if (e >= Ni) return;
  u64 my = keys[e];
  int rank = 0;
  for (int q = 0; q < Ni; ++q) rank += (keys[q] < my) ? 1 : 0;
  int kkeep = Ni >> 1;
  if (rank < kkeep) topi[b * 1024 + rank] = e;
}

// ---------------- gather + tanh gate ------------------------------------------
__global__ void gather_kernel(const float* __restrict__ x, const float* __restrict__ c,
                              const float* __restrict__ s, const int* __restrict__ topi,
                              float* __restrict__ xo, float* __restrict__ co, int Ni) {
  int inew = blockIdx.x, b = blockIdx.y, t = threadIdx.x;
  int kkeep = Ni >> 1;
  int old = topi[b * 1024 + inew];
  float gate = tanhf(s[b * Nmax + old]);
  xo[((size_t)b * kkeep + inew) * 128 + t] = x[((size_t)b * Ni + old) * 128 + t] * gate;
  if (t < 2) co[((size_t)b * kkeep + inew) * 2 + t] = c[((size_t)b * Ni + old) * 2 + t];
}

// ---------------- picks: two-stage [max ; mean] reduction ----------------------
__global__ void picks_partial_kernel(const float* __restrict__ x, float* __restrict__ part,
                                     int kkeep, int G) {
  int b = blockIdx.x, g = blockIdx.y, t = threadIdx.x;
  int per = kkeep / G;
  int start = g * per;
  float mx = -INFINITY, sm = 0.0f;
  for (int i = start; i < start + per; ++i) {
    float v = x[((size_t)b * kkeep + i) * 128 + t];
    mx = fmaxf(mx, v);
    sm += v;
  }
  part[((size_t)(b * G + g)) * 256 + t] = mx;
  part[((size_t)(b * G + g)) * 256 + 128 + t] = sm;
}

__global__ void picks_combine_kernel(const float* __restrict__ part, float* __restrict__ picks,
                                     int kkeep, int G) {
  int b = blockIdx.x, t = threadIdx.x;
  float mx = -INFINITY, sm = 0.0f;
  for (int g = 0; g < G; ++g) {
    mx = fmaxf(mx, part[((size_t)(b * G + g)) * 256 + t]);
    sm += part[((size_t)(b * G + g)) * 256 + 128 + t];
  }
  picks[b * 256 + t] += mx;
  picks[b * 256 + 128 + t] += sm / (float)kkeep;
}

// ---------------- final 2-layer MLP -------------------------------------------
__global__ void final_kernel(const float* __restrict__ picks, const float* __restrict__ Wf1,
                             const float* __restrict__ bf1, const float* __restrict__ Wf2,
                             const float* __restrict__ bf2, float* __restrict__ out) {
  int b = blockIdx.x, t = threadIdx.x;
  __shared__ float pk[256];
  __shared__ float fm[128];
  pk[t] = picks[b * 256 + t];
  pk[t + 128] = picks[b * 256 + 128 + t];
  __syncthreads();
  float acc = bf1[t];
  for (int k = 0; k < 256; ++k) acc += pk[k] * Wf1[k * 128 + t];
  fm[t] = fmaxf(acc, 0.0f);
  __syncthreads();
  if (t < 32) {
    float a2 = bf2[t];
    for (int k = 0; k < 128; ++k) a2 += fm[k] * Wf2[k * 32 + t];
    out[b * 32 + t] = fmaxf(a2, 0.0f);
  }
}

extern "C" void kernel_launch(void* const* d_in, const int* in_sizes, int n_in,
                              void* d_out, int out_size, void* d_ws, size_t ws_size,
                              hipStream_t stream) {
  const float* feats = (const float*)d_in[0];
  const float* cent  = (const float*)d_in[1];
  const float* Wp1 = (const float*)d_in[2];
  const float* bp1 = (const float*)d_in[3];
  const float* bn_g = (const float*)d_in[4];
  const float* bn_b = (const float*)d_in[5];
  const float* Wp2 = (const float*)d_in[6];
  const float* bp2 = (const float*)d_in[7];
  const float* g1  = (const float*)d_in[8];
  const float* be1 = (const float*)d_in[9];
  const float* g2  = (const float*)d_in[10];
  const float* be2 = (const float*)d_in[11];
  const float* Ws  = (const float*)d_in[12];
  const float* Wn  = (const float*)d_in[13];
  const float* bs  = (const float*)d_in[14];
  const float* Wg  = (const float*)d_in[15];
  const float* bg  = (const float*)d_in[16];
  const float* W1  = (const float*)d_in[17];
  const float* b1  = (const float*)d_in[18];
  const float* W2  = (const float*)d_in[19];
  const float* b2  = (const float*)d_in[20];
  const float* Wq  = (const float*)d_in[21];
  const float* bq  = (const float*)d_in[22];
  const float* Wf1 = (const float*)d_in[23];
  const float* bf1 = (const float*)d_in[24];
  const float* Wf2 = (const float*)d_in[25];
  const float* bf2 = (const float*)d_in[26];
  float* out = (float*)d_out;

  float* p = (float*)d_ws;
  const size_t SZX = (size_t)Bn * Nmax * 128;
  float* SC = p;    p += 128;
  float* BBv = p;   p += 128;
  float* DINV = p;  p += Bn * Nmax;
  float* PV = p;    p += Bn * Nmax;
  float* SS = p;    p += Bn * Nmax;
  float* PICKS = p; p += Bn * 256;
  float* PART = p;  p += (size_t)Bn * 32 * 256;
  float* C0 = p;    p += (size_t)Bn * Nmax * 2;
  float* C1 = p;    p += (size_t)Bn * Nmax * 2;
  int* KNN = (int*)p;  p += (size_t)Bn * Nmax * KNN_K;
  int* TOPI = (int*)p; p += Bn * 1024;
  u32* ADJ = (u32*)p;  p += (size_t)Bn * Nmax * 64;
  float* X0 = p;    p += SZX;
  float* X1 = p;    p += SZX;
  float* BA = p;    p += SZX;
  float* BB = p;    p += SZX;
  float* HB = p;    // fused: 4*SZX + WsP/WnP beyond; fallback: 1*SZX
  size_t base_floats = (size_t)(p - (float*)d_ws);
  const size_t WPSZ = (size_t)3 * 128 * 512;
  bool fused = ws_size >= (base_floats + 4 * SZX + 2 * WPSZ) * sizeof(float);
  float* WSP = HB + 4 * SZX;
  float* WNP = WSP + WPSZ;

  hipLaunchKernelGGL(precompute_kernel, dim3(1), dim3(256), 0, stream,
                     bn_g, bn_b, bp1, SC, BBv, PICKS);
  if (fused) {
    hipLaunchKernelGGL(repack_ws_kernel, dim3(768), dim3(256), 0, stream, Ws, Wn, WSP, WNP);
  }

  // ---- preconv ----
  const int M0 = Bn * Nmax;
  hipLaunchKernelGGL(gemm_kernel, dim3(1, M0 / 64), dim3(256), 0, stream,
                     feats, Wp1, (const float*)nullptr, (const float*)nullptr,
                     SC, BBv, BA, M0, 128, 512, GF_RELU);
  hipLaunchKernelGGL(gemm_kernel, dim3(1, M0 / 64), dim3(256), 0, stream,
                     BA, Wp2, (const float*)nullptr, (const float*)nullptr,
                     (const float*)nullptr, bp2, X0, M0, 128, 128, 0);

  float* xc = X0;
  float* xo = X1;
  const float* cc = cent;
  float* co = C0;
  int Ni = Nmax;
  for (int L = 0; L < 3; ++L) {
    int M = Bn * Ni;
    if (Ni == 2048)      hipLaunchKernelGGL(knn_sel_kernel<32>, dim3(Ni, Bn), dim3(64), 0, stream, cc, KNN, Ni);
    else if (Ni == 1024) hipLaunchKernelGGL(knn_sel_kernel<16>, dim3(Ni, Bn), dim3(64), 0, stream, cc, KNN, Ni);
    else                 hipLaunchKernelGGL(knn_sel_kernel<8>,  dim3(Ni, Bn), dim3(64), 0, stream, cc, KNN, Ni);
    hipMemsetAsync(ADJ, 0, (size_t)Bn * Nmax * 64 * sizeof(u32), stream);
    int tot = Bn * Ni * KNN_K;
    hipLaunchKernelGGL(build_adj_kernel, dim3((tot + 255) / 256), dim3(256), 0, stream,
                       KNN, ADJ, Ni);
    hipLaunchKernelGGL(layernorm_kernel, dim3(M), dim3(128), 0, stream,
                       xc, g1 + L * 128, be1 + L * 128, BA);
    hipLaunchKernelGGL(aggregate_kernel, dim3(Ni, Bn), dim3(128), Ni * sizeof(int), stream,
                       ADJ, BA, BB, DINV, Ni);
    if (fused) {
      hipLaunchKernelGGL(gemm_kernel, dim3(4, M / 64), dim3(256), 0, stream,
                         BA, WSP + (size_t)L * 128 * 512,
                         BB, WNP + (size_t)L * 128 * 512,
                         (const float*)nullptr, bs + L * 512,
                         HB, M, 512, 128, GF_RELU);
      hipLaunchKernelGGL(gemm_kernel, dim3(1, M / 64), dim3(256), 0, stream,
                         HB, Wg + (size_t)L * 512 * 128,
                         (const float*)nullptr, (const float*)nullptr,
                         (const float*)nullptr, bg + L * 128,
                         xc, M, 128, 512, GF_ACCUM);
    } else {
      for (int hh = 0; hh < 4; ++hh) {
        hipLaunchKernelGGL(gemm_kernel, dim3(1, M / 64), dim3(256), 0, stream,
                           BA, Ws + ((size_t)(L * 4 + hh)) * 128 * 128,
                           BB, Wn + ((size_t)(L * 4 + hh)) * 128 * 128,
                           (const float*)nullptr, bs + (L * 4 + hh) * 128,
                           HB, M, 128, 128, GF_RELU);
        hipLaunchKernelGGL(gemm_kernel, dim3(1, M / 64), dim3(256), 0, stream,
                           HB, Wg + ((size_t)L * 512 + hh * 128) * 128,
                           (const float*)nullptr, (const float*)nullptr,
                           (const float*)nullptr, (hh == 0) ? (bg + L * 128) : (const float*)nullptr,
                           xc, M, 128, 128, GF_ACCUM);
      }
    }
    hipLaunchKernelGGL(layernorm_kernel, dim3(M), dim3(128), 0, stream,
                       xc, g2 + L * 128, be2 + L * 128, BA);
    hipLaunchKernelGGL(gemm_kernel, dim3(1, M / 64), dim3(256), 0, stream,
                       BA, W1 + (size_t)L * 128 * 128, (const float*)nullptr, (const float*)nullptr,
                       (const float*)nullptr, b1 + L * 128, BB, M, 128, 128, GF_RELU);
    hipLaunchKernelGGL(gemm_kernel, dim3(1, M / 64), dim3(256), 0, stream,
                       BB, W2 + (size_t)L * 128 * 128, (const float*)nullptr, (const float*)nullptr,
                       (const float*)nullptr, b2 + L * 128, xc, M, 128, 128, GF_ACCUM);
    hipLaunchKernelGGL(qp_kernel, dim3(M), dim3(64), 0, stream, xc, Wq + L * 128, DINV, PV, Ni);
    hipLaunchKernelGGL(score_kernel, dim3(Ni, Bn), dim3(64), 0, stream, ADJ, PV, DINV, bq + L, SS, Ni);
    hipLaunchKernelGGL(topk_rank_kernel, dim3((Ni + 255) / 256, Bn), dim3(256), 0, stream,
                       SS, Ni, TOPI);
    int kkeep = Ni >> 1;
    hipLaunchKernelGGL(gather_kernel, dim3(kkeep, Bn), dim3(128), 0, stream,
                       xc, cc, SS, TOPI, xo, co, Ni);
    int G = kkeep / 32;
    hipLaunchKernelGGL(picks_partial_kernel, dim3(Bn, G), dim3(128), 0, stream,
                       xo, PART, kkeep, G);
    hipLaunchKernelGGL(picks_combine_kernel, dim3(Bn), dim3(128), 0, stream,
                       PART, PICKS, kkeep, G);
    float* tmp = xc; xc = xo; xo = tmp;
    cc = co;
    co = (co == C0) ? C1 : C0;
    Ni = kkeep;
  }
  hipLaunchKernelGGL(final_kernel, dim3(Bn), dim3(128), 0, stream,
                     PICKS, Wf1, bf1, Wf2, bf2, out);
}

// Round 5
// 784.232 us; speedup vs baseline: 2.5014x; 1.1317x over previous
//
#include <hip/hip_runtime.h>
#include <math.h>

#define EPSV 1e-5f
#define GF_RELU 1
#define GF_ACCUM 2

typedef unsigned long long u64;
typedef unsigned int u32;

static const int Bn = 8;
static const int Nmax = 2048;
static const int KNN_K = 8;

// ---------------- precompute: fold BN into scale/bias, zero picks ----------------
__global__ void precompute_kernel(const float* __restrict__ bn_g, const float* __restrict__ bn_b,
                                  const float* __restrict__ bp1,
                                  float* __restrict__ sc, float* __restrict__ bb,
                                  float* __restrict__ picks) {
  int t = threadIdx.x;
  if (t < 128) {
    float s = bn_g[t] / sqrtf(1.0f + EPSV);
    sc[t] = s;
    bb[t] = bp1[t] * s + bn_b[t];
  }
  for (int i = t; i < Bn * 256; i += blockDim.x) picks[i] = 0.0f;
}

// ---------------- repack Ws/Wn [L][h][d][e] -> [L][d][h*128+e] -----------------
__global__ void repack_ws_kernel(const float* __restrict__ Ws, const float* __restrict__ Wn,
                                 float* __restrict__ WsP, float* __restrict__ WnP) {
  int idx = blockIdx.x * 256 + threadIdx.x;
  const int total = 3 * 4 * 128 * 128;
  if (idx >= total) return;
  int e = idx & 127, d = (idx >> 7) & 127, h = (idx >> 14) & 3, L = idx >> 16;
  size_t dst = ((size_t)L * 128 + d) * 512 + h * 128 + e;
  WsP[dst] = Ws[idx];
  WnP[dst] = Wn[idx];
}

// ---------------- KNN: keys in registers, 8 wave-min extraction rounds ---------
template<int T>
__global__ __launch_bounds__(64) void knn_sel_kernel(const float* __restrict__ cent,
                                                     int* __restrict__ knn_idx, int Ni) {
  int i = blockIdx.x, b = blockIdx.y, lane = threadIdx.x;
  const float2* cb = (const float2*)(cent + (size_t)b * Ni * 2);
  float2 ci = cb[i];
  u64 keys[T];
#pragma unroll
  for (int t = 0; t < T; ++t) {
    int j = (t << 6) + lane;
    float2 cj = cb[j];
    float dx = __fsub_rn(ci.x, cj.x);
    float dy = __fsub_rn(ci.y, cj.y);
    float d2 = __fadd_rn(__fmul_rn(dx, dx), __fmul_rn(dy, dy));
    keys[t] = ((u64)__float_as_uint(d2) << 32) | (u32)j;
  }
  u64 prev = 0;
  for (int r = 0; r < KNN_K; ++r) {
    u64 best = ~0ULL;
    if (r == 0) {
#pragma unroll
      for (int t = 0; t < T; ++t) { if (keys[t] < best) best = keys[t]; }
    } else {
#pragma unroll
      for (int t = 0; t < T; ++t) { if (keys[t] > prev && keys[t] < best) best = keys[t]; }
    }
    for (int off = 32; off >= 1; off >>= 1) {
      u64 o = __shfl_xor(best, off, 64);
      if (o < best) best = o;
    }
    if (lane == 0) knn_idx[((size_t)(b * Ni + i)) * KNN_K + r] = (int)(best & 0xffffffffULL);
    prev = best;
  }
}

// ---------------- adjacency bitmask: A = mask | mask^T -------------------------
__global__ void build_adj_kernel(const int* __restrict__ knn_idx, u32* __restrict__ adj, int Ni) {
  int e = blockIdx.x * blockDim.x + threadIdx.x;
  int total = Bn * Ni * KNN_K;
  if (e >= total) return;
  int b = e / (Ni * KNN_K);
  int rem = e % (Ni * KNN_K);
  int r = rem / KNN_K;
  int j = knn_idx[e];
  atomicOr(&adj[((size_t)(b * Nmax + r)) * 64 + (j >> 5)], 1u << (j & 31));
  atomicOr(&adj[((size_t)(b * Nmax + j)) * 64 + (r >> 5)], 1u << (r & 31));
}

// ---------------- layernorm over H=128, one block per node ---------------------
__global__ void layernorm_kernel(const float* __restrict__ x, const float* __restrict__ g,
                                 const float* __restrict__ be, float* __restrict__ xn) {
  int node = blockIdx.x;
  int t = threadIdx.x;
  __shared__ float red[128];
  float v = x[(size_t)node * 128 + t];
  red[t] = v;
  __syncthreads();
  for (int s = 64; s > 0; s >>= 1) { if (t < s) red[t] += red[t + s]; __syncthreads(); }
  float mean = red[0] / 128.0f;
  __syncthreads();
  float d = v - mean;
  red[t] = d * d;
  __syncthreads();
  for (int s = 64; s > 0; s >>= 1) { if (t < s) red[t] += red[t + s]; __syncthreads(); }
  float var = red[0] / 128.0f;
  xn[(size_t)node * 128 + t] = d * rsqrtf(var + EPSV) * g[t] + be[t];
}

// ---------------- neighbor-mean aggregation + degree ---------------------------
__global__ void aggregate_kernel(const u32* __restrict__ adj, const float* __restrict__ xn,
                                 float* __restrict__ m, float* __restrict__ dinv, int Ni) {
  int i = blockIdx.x, b = blockIdx.y, t = threadIdx.x;
  __shared__ int cnt;
  extern __shared__ int list[];
  if (t == 0) cnt = 0;
  __syncthreads();
  int wpr = Ni >> 5;
  for (int w = t; w < wpr; w += blockDim.x) {
    u32 bits = adj[((size_t)(b * Nmax + i)) * 64 + w];
    while (bits) {
      int bit = __ffs(bits) - 1;
      bits &= bits - 1;
      int pos = atomicAdd(&cnt, 1);
      list[pos] = (w << 5) + bit;
    }
  }
  __syncthreads();
  int d = cnt;
  float acc = 0.0f;
  for (int k = 0; k < d; ++k) acc += xn[((size_t)b * Ni + list[k]) * 128 + t];
  m[((size_t)b * Ni + i) * 128 + t] = acc / (float)d;
  if (t == 0) dinv[b * Nmax + i] = 1.0f / sqrtf((float)d);
}

// ---------------- fp32 GEMM with register prefetch -----------------------------
// tile: TM rows x 128 cols, 256 threads, (TM/8)x4 acc/thread, K-step 16.
// Requires: M % TM == 0, N % 128 == 0, K % 16 == 0. grid = (N/128, M/TM).
template<int TM>
__global__ __launch_bounds__(256) void gemm_kernel(
    const float* __restrict__ A, const float* __restrict__ W,
    const float* __restrict__ A2, const float* __restrict__ W2,
    const float* __restrict__ scale, const float* __restrict__ bias,
    float* __restrict__ C, int M, int N, int K, int flags) {
  constexpr int RPT = TM / 8;
  __shared__ float As[16][TM + 4];
  __shared__ float Bs[16][132];
  int tid = threadIdx.x;
  int tx = tid & 31;        // 4 cols each
  int ty = tid >> 5;        // RPT rows each
  int colBase = blockIdx.x * 128, rowBase = blockIdx.y * TM;
  float acc[RPT][4] = {};
  int ktiles = K >> 4;
  int total = (A2 ? 2 : 1) * ktiles;

  int arow = tid >> 2, aq = (tid & 3) * 4;   // A stage: TM*4 threads x float4
  int bk = tid >> 5, bc = (tid & 31) * 4;    // B stage: 2 float4/thread

  float4 pa, pb0, pb1;
  // prefetch tile 0
  {
    if (TM == 64 || tid < TM * 4)
      pa = *(const float4*)(A + (size_t)(rowBase + arow) * K + aq);
    pb0 = *(const float4*)(W + (size_t)bk * N + colBase + bc);
    pb1 = *(const float4*)(W + (size_t)(bk + 8) * N + colBase + bc);
  }
  for (int t = 0; t < total; ++t) {
    // store prefetched regs -> LDS
    if (TM == 64 || tid < TM * 4) {
      As[aq + 0][arow] = pa.x;
      As[aq + 1][arow] = pa.y;
      As[aq + 2][arow] = pa.z;
      As[aq + 3][arow] = pa.w;
    }
    *(float4*)&Bs[bk][bc] = pb0;
    *(float4*)&Bs[bk + 8][bc] = pb1;
    __syncthreads();
    // prefetch next tile (overlaps with compute below)
    if (t + 1 < total) {
      int tn = t + 1;
      const float* Ap = (tn >= ktiles) ? A2 : A;
      const float* Wp = (tn >= ktiles) ? W2 : W;
      int k0 = ((tn >= ktiles) ? tn - ktiles : tn) << 4;
      if (TM == 64 || tid < TM * 4)
        pa = *(const float4*)(Ap + (size_t)(rowBase + arow) * K + k0 + aq);
      pb0 = *(const float4*)(Wp + (size_t)(k0 + bk) * N + colBase + bc);
      pb1 = *(const float4*)(Wp + (size_t)(k0 + bk + 8) * N + colBase + bc);
    }
#pragma unroll
    for (int kk = 0; kk < 16; ++kk) {
      float a[RPT], bv[4];
      if (RPT == 8) {
        *(float4*)&a[0] = *(const float4*)&As[kk][ty * 8];
        *(float4*)&a[4] = *(const float4*)&As[kk][ty * 8 + 4];
      } else {
        *(float4*)&a[0] = *(const float4*)&As[kk][ty * 4];
      }
      *(float4*)&bv[0] = *(const float4*)&Bs[kk][tx * 4];
#pragma unroll
      for (int r = 0; r < RPT; ++r)
#pragma unroll
        for (int c = 0; c < 4; ++c) acc[r][c] += a[r] * bv[c];
    }
    __syncthreads();
  }
#pragma unroll
  for (int r = 0; r < RPT; ++r) {
    int row = rowBase + ty * RPT + r;
    int col = colBase + tx * 4;
    float4 v;
    float* vp = (float*)&v;
#pragma unroll
    for (int c = 0; c < 4; ++c) {
      float t = acc[r][c];
      if (scale) t *= scale[col + c];
      if (bias) t += bias[col + c];
      if (flags & GF_RELU) t = fmaxf(t, 0.0f);
      vp[c] = t;
    }
    size_t o = (size_t)row * N + col;
    if (flags & GF_ACCUM) {
      float4 old = *(float4*)&C[o];
      v.x += old.x; v.y += old.y; v.z += old.z; v.w += old.w;
    }
    *(float4*)&C[o] = v;
  }
}

// ---------------- q = x@Wq ; p = dinv*q ---------------------------------------
__global__ void qp_kernel(const float* __restrict__ x, const float* __restrict__ Wq,
                          const float* __restrict__ dinv, float* __restrict__ p, int Ni) {
  int node = blockIdx.x;
  int lane = threadIdx.x;
  int b = node / Ni, i = node % Ni;
  float v = x[(size_t)node * 128 + lane] * Wq[lane] +
            x[(size_t)node * 128 + 64 + lane] * Wq[64 + lane];
  for (int off = 32; off >= 1; off >>= 1) v += __shfl_xor(v, off, 64);
  if (lane == 0) p[b * Nmax + i] = dinv[b * Nmax + i] * v;
}

// ---------------- s = dinv * (A @ p) + bq -------------------------------------
__global__ void score_kernel(const u32* __restrict__ adj, const float* __restrict__ p,
                             const float* __restrict__ dinv, const float* __restrict__ bq,
                             float* __restrict__ s, int Ni) {
  int i = blockIdx.x, b = blockIdx.y, lane = threadIdx.x;
  int wpr = Ni >> 5;
  float acc = 0.0f;
  if (lane < wpr) {
    u32 bits = adj[((size_t)(b * Nmax + i)) * 64 + lane];
    while (bits) {
      int bit = __ffs(bits) - 1;
      bits &= bits - 1;
      acc += p[b * Nmax + (lane << 5) + bit];
    }
  }
  for (int off = 32; off >= 1; off >>= 1) acc += __shfl_xor(acc, off, 64);
  if (lane == 0) s[b * Nmax + i] = dinv[b * Nmax + i] * acc + bq[0];
}

// ---------------- top-k via exact rank counting --------------------------------
__global__ void topk_rank_kernel(const float* __restrict__ s, int Ni, int* __restrict__ topi) {
  int b = blockIdx.y;
  int e0 = blockIdx.x * 256;
  int t = threadIdx.x;
  __shared__ u64 keys[2048];
  for (int e = t; e < Ni; e += 256) {
    u32 u = __float_as_uint(s[b * Nmax + e]);
    u32 mono = (u & 0x80000000u) ? ~u : (u | 0x80000000u);
    keys[e] = ((u64)(~mono) << 32) | (u32)e;
  }
  __syncthreads();
  int e = e0 + t;
  if (e >= Ni) return;
  u64 my = keys[e];
  int rank = 0;
  for (int q = 0; q < Ni; ++q) rank += (keys[q] < my) ? 1 : 0;
  int kkeep = Ni >> 1;
  if (rank < kkeep) topi[b * 1024 + rank] = e;
}

// ---------------- gather + tanh gate ------------------------------------------
__global__ void gather_kernel(const float* __restrict__ x, const float* __restrict__ c,
                              const float* __restrict__ s, const int* __restrict__ topi,
                              float* __restrict__ xo, float* __restrict__ co, int Ni) {
  int inew = blockIdx.x, b = blockIdx.y, t = threadIdx.x;
  int kkeep = Ni >> 1;
  int old = topi[b * 1024 + inew];
  float gate = tanhf(s[b * Nmax + old]);
  xo[((size_t)b * kkeep + inew) * 128 + t] = x[((size_t)b * Ni + old) * 128 + t] * gate;
  if (t < 2) co[((size_t)b * kkeep + inew) * 2 + t] = c[((size_t)b * Ni + old) * 2 + t];
}

// ---------------- picks: two-stage [max ; mean] reduction ----------------------
__global__ void picks_partial_kernel(const float* __restrict__ x, float* __restrict__ part,
                                     int kkeep, int G) {
  int b = blockIdx.x, g = blockIdx.y, t = threadIdx.x;
  int per = kkeep / G;
  int start = g * per;
  float mx = -INFINITY, sm = 0.0f;
  for (int i = start; i < start + per; ++i) {
    float v = x[((size_t)b * kkeep + i) * 128 + t];
    mx = fmaxf(mx, v);
    sm += v;
  }
  part[((size_t)(b * G + g)) * 256 + t] = mx;
  part[((size_t)(b * G + g)) * 256 + 128 + t] = sm;
}

__global__ void picks_combine_kernel(const float* __restrict__ part, float* __restrict__ picks,
                                     int kkeep, int G) {
  int b = blockIdx.x, t = threadIdx.x;
  float mx = -INFINITY, sm = 0.0f;
  for (int g = 0; g < G; ++g) {
    mx = fmaxf(mx, part[((size_t)(b * G + g)) * 256 + t]);
    sm += part[((size_t)(b * G + g)) * 256 + 128 + t];
  }
  picks[b * 256 + t] += mx;
  picks[b * 256 + 128 + t] += sm / (float)kkeep;
}

// ---------------- final 2-layer MLP -------------------------------------------
__global__ void final_kernel(const float* __restrict__ picks, const float* __restrict__ Wf1,
                             const float* __restrict__ bf1, const float* __restrict__ Wf2,
                             const float* __restrict__ bf2, float* __restrict__ out) {
  int b = blockIdx.x, t = threadIdx.x;
  __shared__ float pk[256];
  __shared__ float fm[128];
  pk[t] = picks[b * 256 + t];
  pk[t + 128] = picks[b * 256 + 128 + t];
  __syncthreads();
  float acc = bf1[t];
  for (int k = 0; k < 256; ++k) acc += pk[k] * Wf1[k * 128 + t];
  fm[t] = fmaxf(acc, 0.0f);
  __syncthreads();
  if (t < 32) {
    float a2 = bf2[t];
    for (int k = 0; k < 128; ++k) a2 += fm[k] * Wf2[k * 32 + t];
    out[b * 32 + t] = fmaxf(a2, 0.0f);
  }
}

extern "C" void kernel_launch(void* const* d_in, const int* in_sizes, int n_in,
                              void* d_out, int out_size, void* d_ws, size_t ws_size,
                              hipStream_t stream) {
  const float* feats = (const float*)d_in[0];
  const float* cent  = (const float*)d_in[1];
  const float* Wp1 = (const float*)d_in[2];
  const float* bp1 = (const float*)d_in[3];
  const float* bn_g = (const float*)d_in[4];
  const float* bn_b = (const float*)d_in[5];
  const float* Wp2 = (const float*)d_in[6];
  const float* bp2 = (const float*)d_in[7];
  const float* g1  = (const float*)d_in[8];
  const float* be1 = (const float*)d_in[9];
  const float* g2  = (const float*)d_in[10];
  const float* be2 = (const float*)d_in[11];
  const float* Ws  = (const float*)d_in[12];
  const float* Wn  = (const float*)d_in[13];
  const float* bs  = (const float*)d_in[14];
  const float* Wg  = (const float*)d_in[15];
  const float* bg  = (const float*)d_in[16];
  const float* W1  = (const float*)d_in[17];
  const float* b1  = (const float*)d_in[18];
  const float* W2  = (const float*)d_in[19];
  const float* b2  = (const float*)d_in[20];
  const float* Wq  = (const float*)d_in[21];
  const float* bq  = (const float*)d_in[22];
  const float* Wf1 = (const float*)d_in[23];
  const float* bf1 = (const float*)d_in[24];
  const float* Wf2 = (const float*)d_in[25];
  const float* bf2 = (const float*)d_in[26];
  float* out = (float*)d_out;

  float* p = (float*)d_ws;
  const size_t SZX = (size_t)Bn * Nmax * 128;
  float* SC = p;    p += 128;
  float* BBv = p;   p += 128;
  float* DINV = p;  p += Bn * Nmax;
  float* PV = p;    p += Bn * Nmax;
  float* SS = p;    p += Bn * Nmax;
  float* PICKS = p; p += Bn * 256;
  float* PART = p;  p += (size_t)Bn * 32 * 256;
  float* C0 = p;    p += (size_t)Bn * Nmax * 2;
  float* C1 = p;    p += (size_t)Bn * Nmax * 2;
  int* KNN = (int*)p;  p += (size_t)Bn * Nmax * KNN_K;
  int* TOPI = (int*)p; p += Bn * 1024;
  u32* ADJ = (u32*)p;  p += (size_t)Bn * Nmax * 64;
  float* X0 = p;    p += SZX;
  float* X1 = p;    p += SZX;
  float* BA = p;    p += SZX;
  float* BB = p;    p += SZX;
  float* HB = p;    // fused: 4*SZX + WsP/WnP beyond; fallback: 1*SZX
  size_t base_floats = (size_t)(p - (float*)d_ws);
  const size_t WPSZ = (size_t)3 * 128 * 512;
  bool fused = ws_size >= (base_floats + 4 * SZX + 2 * WPSZ) * sizeof(float);
  float* WSP = HB + 4 * SZX;
  float* WNP = WSP + WPSZ;

  hipLaunchKernelGGL(precompute_kernel, dim3(1), dim3(256), 0, stream,
                     bn_g, bn_b, bp1, SC, BBv, PICKS);
  if (fused) {
    hipLaunchKernelGGL(repack_ws_kernel, dim3(768), dim3(256), 0, stream, Ws, Wn, WSP, WNP);
  }

  // ---- preconv ----
  const int M0 = Bn * Nmax;
  hipLaunchKernelGGL(gemm_kernel<32>, dim3(1, M0 / 32), dim3(256), 0, stream,
                     feats, Wp1, (const float*)nullptr, (const float*)nullptr,
                     SC, BBv, BA, M0, 128, 512, GF_RELU);
  hipLaunchKernelGGL(gemm_kernel<32>, dim3(1, M0 / 32), dim3(256), 0, stream,
                     BA, Wp2, (const float*)nullptr, (const float*)nullptr,
                     (const float*)nullptr, bp2, X0, M0, 128, 128, 0);

  float* xc = X0;
  float* xo = X1;
  const float* cc = cent;
  float* co = C0;
  int Ni = Nmax;
  for (int L = 0; L < 3; ++L) {
    int M = Bn * Ni;
    if (Ni == 2048)      hipLaunchKernelGGL(knn_sel_kernel<32>, dim3(Ni, Bn), dim3(64), 0, stream, cc, KNN, Ni);
    else if (Ni == 1024) hipLaunchKernelGGL(knn_sel_kernel<16>, dim3(Ni, Bn), dim3(64), 0, stream, cc, KNN, Ni);
    else                 hipLaunchKernelGGL(knn_sel_kernel<8>,  dim3(Ni, Bn), dim3(64), 0, stream, cc, KNN, Ni);
    hipMemsetAsync(ADJ, 0, (size_t)Bn * Nmax * 64 * sizeof(u32), stream);
    int tot = Bn * Ni * KNN_K;
    hipLaunchKernelGGL(build_adj_kernel, dim3((tot + 255) / 256), dim3(256), 0, stream,
                       KNN, ADJ, Ni);
    hipLaunchKernelGGL(layernorm_kernel, dim3(M), dim3(128), 0, stream,
                       xc, g1 + L * 128, be1 + L * 128, BA);
    hipLaunchKernelGGL(aggregate_kernel, dim3(Ni, Bn), dim3(128), Ni * sizeof(int), stream,
                       ADJ, BA, BB, DINV, Ni);
    if (fused) {
      hipLaunchKernelGGL(gemm_kernel<32>, dim3(4, M / 32), dim3(256), 0, stream,
                         BA, WSP + (size_t)L * 128 * 512,
                         BB, WNP + (size_t)L * 128 * 512,
                         (const float*)nullptr, bs + L * 512,
                         HB, M, 512, 128, GF_RELU);
      hipLaunchKernelGGL(gemm_kernel<32>, dim3(1, M / 32), dim3(256), 0, stream,
                         HB, Wg + (size_t)L * 512 * 128,
                         (const float*)nullptr, (const float*)nullptr,
                         (const float*)nullptr, bg + L * 128,
                         xc, M, 128, 512, GF_ACCUM);
    } else {
      for (int hh = 0; hh < 4; ++hh) {
        hipLaunchKernelGGL(gemm_kernel<32>, dim3(1, M / 32), dim3(256), 0, stream,
                           BA, Ws + ((size_t)(L * 4 + hh)) * 128 * 128,
                           BB, Wn + ((size_t)(L * 4 + hh)) * 128 * 128,
                           (const float*)nullptr, bs + (L * 4 + hh) * 128,
                           HB, M, 128, 128, GF_RELU);
        hipLaunchKernelGGL(gemm_kernel<32>, dim3(1, M / 32), dim3(256), 0, stream,
                           HB, Wg + ((size_t)L * 512 + hh * 128) * 128,
                           (const float*)nullptr, (const float*)nullptr,
                           (const float*)nullptr, (hh == 0) ? (bg + L * 128) : (const float*)nullptr,
                           xc, M, 128, 128, GF_ACCUM);
      }
    }
    hipLaunchKernelGGL(layernorm_kernel, dim3(M), dim3(128), 0, stream,
                       xc, g2 + L * 128, be2 + L * 128, BA);
    hipLaunchKernelGGL(gemm_kernel<32>, dim3(1, M / 32), dim3(256), 0, stream,
                       BA, W1 + (size_t)L * 128 * 128, (const float*)nullptr, (const float*)nullptr,
                       (const float*)nullptr, b1 + L * 128, BB, M, 128, 128, GF_RELU);
    hipLaunchKernelGGL(gemm_kernel<32>, dim3(1, M / 32), dim3(256), 0, stream,
                       BB, W2 + (size_t)L * 128 * 128, (const float*)nullptr, (const float*)nullptr,
                       (const float*)nullptr, b2 + L * 128, xc, M, 128, 128, GF_ACCUM);
    hipLaunchKernelGGL(qp_kernel, dim3(M), dim3(64), 0, stream, xc, Wq + L * 128, DINV, PV, Ni);
    hipLaunchKernelGGL(score_kernel, dim3(Ni, Bn), dim3(64), 0, stream, ADJ, PV, DINV, bq + L, SS, Ni);
    hipLaunchKernelGGL(topk_rank_kernel, dim3((Ni + 255) / 256, Bn), dim3(256), 0, stream,
                       SS, Ni, TOPI);
    int kkeep = Ni >> 1;
    hipLaunchKernelGGL(gather_kernel, dim3(kkeep, Bn), dim3(128), 0, stream,
                       xc, cc, SS, TOPI, xo, co, Ni);
    int G = kkeep / 32;
    hipLaunchKernelGGL(picks_partial_kernel, dim3(Bn, G), dim3(128), 0, stream,
                       xo, PART, kkeep, G);
    hipLaunchKernelGGL(picks_combine_kernel, dim3(Bn), dim3(128), 0, stream,
                       PART, PICKS, kkeep, G);
    float* tmp = xc; xc = xo; xo = tmp;
    cc = co;
    co = (co == C0) ? C1 : C0;
    Ni = kkeep;
  }
  hipLaunchKernelGGL(final_kernel, dim3(Bn), dim3(128), 0, stream,
                     PICKS, Wf1, bf1, Wf2, bf2, out);
}